// Round 1
// baseline (1568.202 us; speedup 1.0000x reference)
//
#include <hip/hip_runtime.h>
#include <hip/hip_bf16.h>
#include <math.h>

#define BB 256
#define TT 50
#define VV 100000
#define EMB 64
#define KBD 64
#define HH 128
#define NF 10
#define OUTD 64
#define G3H 384

typedef __attribute__((ext_vector_type(8))) short sh8;
typedef __attribute__((ext_vector_type(4))) float f32x4;

__device__ __forceinline__ float sigmoidf_(float x){ return 1.0f/(1.0f+__expf(-x)); }

// ---------------- transpose weights (k-major for coalesced mat-vec) ----------------
__global__ void k_trans(const float* __restrict__ Whh, const float* __restrict__ Wih,
                        const float* __restrict__ uW, const float* __restrict__ eaW,
                        const float* __restrict__ u2W, const float* __restrict__ m1W,
                        float* __restrict__ WhhT, float* __restrict__ WihT,
                        float* __restrict__ uWT, float* __restrict__ eaWT,
                        float* __restrict__ u2WT, float* __restrict__ m1WT) {
  int stride = gridDim.x*blockDim.x;
  int tid0 = blockIdx.x*blockDim.x + threadIdx.x;
  for (int i=tid0; i<G3H*HH;      i+=stride){ int j=i/HH,  k=i%HH;  WhhT[k*G3H+j]=Whh[i]; }
  for (int i=tid0; i<G3H*EMB;     i+=stride){ int j=i/EMB, k=i%EMB; WihT[k*G3H+j]=Wih[i]; }
  for (int i=tid0; i<KBD*HH;      i+=stride){ int j=i/HH,  k=i%HH;  uWT[k*KBD+j]=uW[i]; }
  for (int i=tid0; i<KBD*KBD;     i+=stride){ int j=i/KBD, k=i%KBD; eaWT[k*KBD+j]=eaW[i]; }
  for (int i=tid0; i<HH*(HH+KBD); i+=stride){ int j=i/(HH+KBD), k=i%(HH+KBD); u2WT[k*HH+j]=u2W[i]; }
  for (int i=tid0; i<OUTD*HH;     i+=stride){ int j=i/HH,  k=i%HH;  m1WT[k*OUTD+j]=m1W[i]; }
}

// ---------------- precompute gi[b,t,384] and ea[b,t,64] (input-dependent matmuls) ----
#define PREP 32
__global__ __launch_bounds__(384) void k_pre(
    const int* __restrict__ X, const float* __restrict__ E, const float* __restrict__ KBE,
    const float* __restrict__ WihT, const float* __restrict__ bih,
    const float* __restrict__ eaWT, const float* __restrict__ eab,
    float* __restrict__ gi_pre, float* __restrict__ ea_pre) {
  __shared__ float xeL[PREP][EMB];
  __shared__ float kbL[PREP][KBD];
  int tid = threadIdx.x;
  int base = blockIdx.x * PREP;
  for (int i=tid; i<PREP*EMB; i+=384){
    int p=i>>6, k=i&63; int x = X[base+p];
    xeL[p][k] = x ? E[(size_t)x*EMB+k] : 0.0f;
    kbL[p][k] = x ? KBE[(size_t)x*KBD+k] : 0.0f;
  }
  __syncthreads();
  { // gi: thread j owns output column j for all 32 pairs
    int j = tid;
    float acc[PREP];
    #pragma unroll
    for (int p=0;p<PREP;p++) acc[p]=0.f;
    for (int k=0;k<EMB;k++){
      float w = WihT[k*G3H+j];
      #pragma unroll
      for (int p=0;p<PREP;p++) acc[p] += w*xeL[p][k];
    }
    float bj = bih[j];
    for (int p=0;p<PREP;p++) gi_pre[((size_t)(base+p))*G3H + j] = acc[p]+bj;
  }
  { // ea
    int d = tid & 63; int pg = tid >> 6;   // 6 groups of 64
    float bd = eab[d];
    for (int p=pg; p<PREP; p+=6){
      float acc=0.f;
      #pragma unroll 8
      for (int k=0;k<KBD;k++) acc += eaWT[k*KBD+d]*kbL[p][k];
      ea_pre[((size_t)(base+p))*KBD + d] = tanhf(acc + bd);
    }
  }
}

// ---------------- Sy[v][o] = tanh(MergeE[v] . m2W[o] + m2b[o]) as bf16 --------------
#define SYV 16
__global__ __launch_bounds__(256) void k_sy(
    const float* __restrict__ E, const float* __restrict__ KBE,
    const float* __restrict__ m2W, const float* __restrict__ m2b,
    __hip_bfloat16* __restrict__ Sy) {
  __shared__ float wL[OUTD][129];    // +1 pad: conflict-free
  __shared__ float meL[SYV][128];
  int tid = threadIdx.x;
  int v0 = blockIdx.x * SYV;
  for (int i=tid; i<OUTD*128; i+=256){ int o=i>>7, k=i&127; wL[o][k] = m2W[i]; }
  for (int i=tid; i<SYV*128; i+=256){
    int vl=i>>7, k=i&127; int v=v0+vl;
    float val;
    if (v==0) val=0.f;
    else val = (k<64)? E[(size_t)v*EMB + k] : KBE[(size_t)v*KBD + (k-64)];
    meL[vl][k]=val;
  }
  __syncthreads();
  int o = tid & 63, vl0 = tid >> 6;
  float bo = m2b[o];
  for (int vi=vl0; vi<SYV; vi+=4){
    float acc=bo;
    #pragma unroll 8
    for (int k=0;k<128;k++) acc += meL[vi][k]*wL[o][k];
    Sy[(size_t)(v0+vi)*OUTD + o] = __float2bfloat16(tanhf(acc));
  }
}

// ---------------- the sequential scan: one block per batch row ----------------------
__global__ __launch_bounds__(384) void k_scan(
    const float* __restrict__ gi_pre, const float* __restrict__ ea_pre,
    const float* __restrict__ WhhT, const float* __restrict__ bhh,
    const float* __restrict__ uWT, const float* __restrict__ ub,
    const float* __restrict__ rmat,
    const float* __restrict__ u2WT, const float* __restrict__ u2b,
    const float* __restrict__ m1WT, const float* __restrict__ m1b,
    __hip_bfloat16* __restrict__ ybf) {
  __shared__ float uwL[HH][OUTD];    // 32KB  [k][d]
  __shared__ float m1wL[HH][OUTD];   // 32KB  [k][o]
  __shared__ float rmL[NF][KBD];
  __shared__ float mnL[NF][KBD];
  __shared__ float hL[HH];
  __shared__ float ghL[G3H];
  __shared__ float giL[G3H];
  __shared__ float eaL[KBD];
  __shared__ float UL[KBD];
  __shared__ float acL[KBD];
  __shared__ float UtL[HH];
  __shared__ float ysumL[OUTD];
  __shared__ float gL[NF], awL[NF], lgL[NF];

  int tid = threadIdx.x;
  int b = blockIdx.x;

  for (int i=tid;i<HH*OUTD;i+=384){ uwL[i>>6][i&63]=uWT[i]; m1wL[i>>6][i&63]=m1WT[i]; }
  for (int i=tid;i<NF*KBD;i+=384){ rmL[i>>6][i&63]=rmat[i]; mnL[i>>6][i&63]=0.f; }
  if (tid<HH) hL[tid]=0.f;
  if (tid<OUTD) ysumL[tid]=0.f;
  float bhh_r = bhh[tid];
  float ub_r  = (tid<KBD)? ub[tid]:0.f;
  float u2b_r = (tid<HH)? u2b[tid]:0.f;
  float m1b_r = (tid<OUTD)? m1b[tid]:0.f;
  __syncthreads();

  const float* gi_b = gi_pre + (size_t)b*TT*G3H;
  const float* ea_b = ea_pre + (size_t)b*TT*KBD;

  for (int t=0;t<TT;t++){
    // S0: stream this step's precomputed gi / ea
    giL[tid] = gi_b[t*G3H + tid];
    if (tid<KBD) eaL[tid] = ea_b[t*KBD + tid];
    // S1: gh[j] = Whh[j,:].h + bhh[j]   (reads previous h)
    {
      float acc = bhh_r;
      #pragma unroll 8
      for (int k=0;k<HH;k++) acc += WhhT[k*G3H+tid]*hL[k];
      ghL[tid]=acc;
    }
    __syncthreads();               // A: gi, ea, gh visible
    // S2: GRU gates -> new h
    if (tid<HH){
      float r = sigmoidf_(giL[tid]      + ghL[tid]);
      float z = sigmoidf_(giL[HH+tid]   + ghL[HH+tid]);
      float n = tanhf   (giL[2*HH+tid] + r*ghL[2*HH+tid]);
      hL[tid] = (1.f-z)*n + z*hL[tid];
    }
    __syncthreads();               // B
    // S3a: memory-write gate[n] = sigmoid(sum_d MN[n,d]*(ea[d]+rm[n,d]))   (OLD MN)
    if (tid<NF*16){
      int n = tid>>4, l16 = tid&15;
      float p=0.f;
      #pragma unroll
      for (int ii=0;ii<4;ii++){ int d=l16*4+ii; p += mnL[n][d]*(eaL[d]+rmL[n][d]); }
      p += __shfl_xor(p,1,16); p += __shfl_xor(p,2,16);
      p += __shfl_xor(p,4,16); p += __shfl_xor(p,8,16);
      if (l16==0) gL[n]=sigmoidf_(p);
    }
    __syncthreads();               // C
    // S3b: MN update
    for (int oi=tid; oi<NF*KBD; oi+=384){
      int n=oi>>6, d=oi&63;
      float g=gL[n];
      float eav = eaL[d]+rmL[n][d];
      mnL[n][d] += g*(eav - mnL[n][d]);
    }
    // S4: U = tanh(uW . h + ub)   (new h)
    if (tid<KBD){
      float acc=ub_r;
      #pragma unroll 8
      for (int k=0;k<HH;k++) acc += uwL[k][tid]*hL[k];
      UL[tid]=tanhf(acc);
    }
    __syncthreads();               // D
    // S5a: attention logits
    if (tid<NF*16){
      int n = tid>>4, l16 = tid&15;
      float p=0.f;
      #pragma unroll
      for (int ii=0;ii<4;ii++){ int d=l16*4+ii; p += UL[d]*rmL[n][d]; }
      p += __shfl_xor(p,1,16); p += __shfl_xor(p,2,16);
      p += __shfl_xor(p,4,16); p += __shfl_xor(p,8,16);
      if (l16==0) lgL[n]=p;
    }
    __syncthreads();               // E
    // S5b: softmax over 10 (serial, tiny)
    if (tid==0){
      float m=lgL[0];
      #pragma unroll
      for (int n=1;n<NF;n++) m = fmaxf(m,lgL[n]);
      float s=0.f;
      float e[NF];
      #pragma unroll
      for (int n=0;n<NF;n++){ e[n]=__expf(lgL[n]-m); s+=e[n]; }
      float inv=1.f/s;
      #pragma unroll
      for (int n=0;n<NF;n++) awL[n]=e[n]*inv;
    }
    __syncthreads();               // F
    // S6: AC[d] = sum_n MN[n,d]*aw[n]   (new MN)
    if (tid<KBD){
      float acc=0.f;
      #pragma unroll
      for (int n=0;n<NF;n++) acc += mnL[n][tid]*awL[n];
      acL[tid]=acc;
    }
    __syncthreads();               // G
    // S7: Ut = tanh(u2W . [h;AC] + u2b)
    if (tid<HH){
      float acc=u2b_r;
      #pragma unroll 8
      for (int k=0;k<HH;k++)  acc += u2WT[k*HH+tid]*hL[k];
      #pragma unroll 8
      for (int k=0;k<KBD;k++) acc += u2WT[(HH+k)*HH+tid]*acL[k];
      UtL[tid]=tanhf(acc);
    }
    __syncthreads();               // H
    // S8: y = tanh(m1W . Ut + m1b); ysum += y
    if (tid<OUTD){
      float acc=m1b_r;
      #pragma unroll 8
      for (int k=0;k<HH;k++) acc += m1wL[k][tid]*UtL[k];
      ysumL[tid] += tanhf(acc);
    }
    // no end sync needed: next iter's first barrier (A) orders everything
  }
  __syncthreads();
  if (tid<OUTD) ybf[b*OUTD+tid] = __float2bfloat16(ysumL[tid]*(1.0f/TT));
}

// ---------------- final: s = y @ Sy^T, log_softmax (|s|<=64 so no max shift) --------
// pass 0: denom[b] += sum_v exp(s);  pass 1: out = s - log(denom[b])
__global__ __launch_bounds__(256) void k_logits(
    const __hip_bfloat16* __restrict__ ybf, const __hip_bfloat16* __restrict__ Sy,
    float* __restrict__ denom, float* __restrict__ out, int pass) {
  int lane = threadIdx.x & 63;
  int w = threadIdx.x >> 6;
  int r16 = lane & 15;
  int kof = (lane >> 4) * 8;
  int tbase = blockIdx.x * 16 + w * 4;      // tiles of 16 vocab each
  sh8 b0[4], b1[4];
  int nt = 0;
  #pragma unroll
  for (int i=0;i<4;i++){
    int tIdx = tbase + i;
    if (tIdx < VV/16) {
      const __hip_bfloat16* bp = Sy + ((size_t)(tIdx*16 + r16))*OUTD + kof;
      b0[i] = *(const sh8*)bp;
      b1[i] = *(const sh8*)(bp + 32);
      nt = i+1;
    }
  }
  for (int bg=0; bg<16; bg++){
    int arow = bg*16 + r16;
    const __hip_bfloat16* ap = ybf + arow*OUTD + kof;
    sh8 a0 = *(const sh8*)ap;
    sh8 a1 = *(const sh8*)(ap+32);
    if (pass == 0){
      float part[4] = {0.f,0.f,0.f,0.f};
      for (int i=0;i<nt;i++){
        f32x4 acc = {0.f,0.f,0.f,0.f};
        acc = __builtin_amdgcn_mfma_f32_16x16x32_bf16(a0,b0[i],acc,0,0,0);
        acc = __builtin_amdgcn_mfma_f32_16x16x32_bf16(a1,b1[i],acc,0,0,0);
        #pragma unroll
        for (int r=0;r<4;r++) part[r] += __expf(acc[r]);
      }
      #pragma unroll
      for (int r=0;r<4;r++){
        float p = part[r];
        p += __shfl_xor(p,1,16); p += __shfl_xor(p,2,16);
        p += __shfl_xor(p,4,16); p += __shfl_xor(p,8,16);
        if (r16==0) atomicAdd(&denom[bg*16 + (lane>>4)*4 + r], p);
      }
    } else {
      float lse[4];
      #pragma unroll
      for (int r=0;r<4;r++) lse[r] = logf(denom[bg*16 + (lane>>4)*4 + r]);
      for (int i=0;i<nt;i++){
        f32x4 acc = {0.f,0.f,0.f,0.f};
        acc = __builtin_amdgcn_mfma_f32_16x16x32_bf16(a0,b0[i],acc,0,0,0);
        acc = __builtin_amdgcn_mfma_f32_16x16x32_bf16(a1,b1[i],acc,0,0,0);
        int vc = (tbase+i)*16 + r16;
        #pragma unroll
        for (int r=0;r<4;r++)
          out[(size_t)(bg*16 + (lane>>4)*4 + r)*VV + vc] = acc[r] - lse[r];
      }
    }
  }
}

extern "C" void kernel_launch(void* const* d_in, const int* in_sizes, int n_in,
                              void* d_out, int out_size, void* d_ws, size_t ws_size,
                              hipStream_t stream) {
  const int*   X    = (const int*)  d_in[0];
  const float* E    = (const float*)d_in[1];
  const float* KBE  = (const float*)d_in[2];
  const float* rmat = (const float*)d_in[3];
  const float* Wih  = (const float*)d_in[4];
  const float* Whh  = (const float*)d_in[5];
  const float* bih  = (const float*)d_in[6];
  const float* bhh  = (const float*)d_in[7];
  const float* uW   = (const float*)d_in[8];
  const float* ub   = (const float*)d_in[9];
  const float* eaW  = (const float*)d_in[10];
  const float* eab  = (const float*)d_in[11];
  const float* u2W  = (const float*)d_in[12];
  const float* u2b  = (const float*)d_in[13];
  const float* m1W  = (const float*)d_in[14];
  const float* m1b  = (const float*)d_in[15];
  const float* m2W  = (const float*)d_in[16];
  const float* m2b  = (const float*)d_in[17];
  float* outp = (float*)d_out;

  float* wsf = (float*)d_ws;
  size_t o = 0;
  float* WhhT = wsf+o; o += (size_t)G3H*HH;
  float* WihT = wsf+o; o += (size_t)G3H*EMB;
  float* uWT  = wsf+o; o += (size_t)KBD*HH;
  float* eaWT = wsf+o; o += (size_t)KBD*KBD;
  float* u2WT = wsf+o; o += (size_t)(HH+KBD)*HH;
  float* m1WT = wsf+o; o += (size_t)OUTD*HH;
  float* gi_pre = wsf+o; o += (size_t)BB*TT*G3H;
  float* ea_pre = wsf+o; o += (size_t)BB*TT*KBD;
  float* denom  = wsf+o; o += BB;
  __hip_bfloat16* ybf = (__hip_bfloat16*)(wsf+o); o += (size_t)BB*OUTD/2;
  __hip_bfloat16* Sy  = (__hip_bfloat16*)(wsf+o); o += (size_t)VV*OUTD/2;

  k_trans<<<64,256,0,stream>>>(Whh,Wih,uW,eaW,u2W,m1W, WhhT,WihT,uWT,eaWT,u2WT,m1WT);
  k_pre<<<(BB*TT)/PREP,384,0,stream>>>(X,E,KBE,WihT,bih,eaWT,eab,gi_pre,ea_pre);
  k_sy<<<VV/SYV,256,0,stream>>>(E,KBE,m2W,m2b,Sy);
  k_scan<<<BB,384,0,stream>>>(gi_pre,ea_pre,WhhT,bhh,uWT,ub,rmat,u2WT,u2b,m1WT,m1b,ybf);
  hipMemsetAsync(denom, 0, BB*sizeof(float), stream);
  dim3 g1((VV/16 + 15)/16, 1, 1);
  k_logits<<<g1,256,0,stream>>>(ybf,Sy,denom,outp,0);
  k_logits<<<g1,256,0,stream>>>(ybf,Sy,denom,outp,1);
}

// Round 2
// 821.626 us; speedup vs baseline: 1.9087x; 1.9087x over previous
//
#include <hip/hip_runtime.h>
#include <hip/hip_bf16.h>
#include <math.h>

#define BB 256
#define TT 50
#define VV 100000
#define EMB 64
#define KBD 64
#define HH 128
#define NF 10
#define OUTD 64
#define G3H 384
#define NTILE 6250   // VV/16

typedef __attribute__((ext_vector_type(8))) short sh8;
typedef __attribute__((ext_vector_type(4))) float f32x4;

__device__ __forceinline__ float sigmoidf_(float x){ return 1.0f/(1.0f+__expf(-x)); }
__device__ __forceinline__ float b2f(short s){ return __uint_as_float(((unsigned)(unsigned short)s)<<16); }
__device__ __forceinline__ short f2bs(float f){ __hip_bfloat16 h=__float2bfloat16(f); return *reinterpret_cast<short*>(&h); }

// ---------------- pack weights ----------------
// WihT f32 [64 k][384 j]          (for k_pre)
// eaWT f32 [64 k][64 d]           (for k_pre)
// whh_bf bf16 [(kb*384+j)*8+c] = Whh[j*128+kb*8+c]   kb<16
// u2_bf  bf16 [(kb*128+j)*8+c] = u2W[j*192+kb*8+c]   kb<24
// uw_bf  bf16 [(kb*64+j)*8+c]  = uW[j*128+kb*8+c]    kb<16
// m1_bf  bf16 same shape as uw_bf from m1W
__global__ void k_trans(const float* __restrict__ Whh, const float* __restrict__ Wih,
                        const float* __restrict__ uW, const float* __restrict__ eaW,
                        const float* __restrict__ u2W, const float* __restrict__ m1W,
                        float* __restrict__ WihT, float* __restrict__ eaWT,
                        __hip_bfloat16* __restrict__ whh_bf, __hip_bfloat16* __restrict__ u2_bf,
                        __hip_bfloat16* __restrict__ uw_bf, __hip_bfloat16* __restrict__ m1_bf) {
  int stride = gridDim.x*blockDim.x;
  int tid0 = blockIdx.x*blockDim.x + threadIdx.x;
  for (int i=tid0; i<G3H*EMB; i+=stride){ int j=i/EMB, k=i%EMB; WihT[k*G3H+j]=Wih[i]; }
  for (int i=tid0; i<KBD*KBD; i+=stride){ int j=i/KBD, k=i%KBD; eaWT[k*KBD+j]=eaW[i]; }
  for (int i=tid0; i<16*G3H*8; i+=stride){
    int c=i&7, r=i>>3, j=r%G3H, kb=r/G3H;
    whh_bf[i] = __float2bfloat16(Whh[j*HH + kb*8 + c]);
  }
  for (int i=tid0; i<24*HH*8; i+=stride){
    int c=i&7, r=i>>3, j=r%HH, kb=r/HH;
    u2_bf[i] = __float2bfloat16(u2W[j*(HH+KBD) + kb*8 + c]);
  }
  for (int i=tid0; i<16*OUTD*8; i+=stride){
    int c=i&7, r=i>>3, j=r%OUTD, kb=r/OUTD;
    uw_bf[i] = __float2bfloat16(uW[j*HH + kb*8 + c]);
    m1_bf[i] = __float2bfloat16(m1W[j*HH + kb*8 + c]);
  }
}

// ---------------- precompute gi[b,t,384] and ea[b,t,64] ----------------
#define PREP 32
__global__ __launch_bounds__(384) void k_pre(
    const int* __restrict__ X, const float* __restrict__ E, const float* __restrict__ KBE,
    const float* __restrict__ WihT, const float* __restrict__ bih,
    const float* __restrict__ eaWT, const float* __restrict__ eab,
    float* __restrict__ gi_pre, float* __restrict__ ea_pre) {
  __shared__ float xeL[PREP][EMB];
  __shared__ float kbL[PREP][KBD];
  int tid = threadIdx.x;
  int base = blockIdx.x * PREP;
  for (int i=tid; i<PREP*EMB; i+=384){
    int p=i>>6, k=i&63; int x = X[base+p];
    xeL[p][k] = x ? E[(size_t)x*EMB+k] : 0.0f;
    kbL[p][k] = x ? KBE[(size_t)x*KBD+k] : 0.0f;
  }
  __syncthreads();
  { // gi: thread j owns output column j for all 32 pairs
    int j = tid;
    float acc[PREP];
    #pragma unroll
    for (int p=0;p<PREP;p++) acc[p]=0.f;
    for (int k=0;k<EMB;k++){
      float w = WihT[k*G3H+j];
      #pragma unroll
      for (int p=0;p<PREP;p++) acc[p] += w*xeL[p][k];
    }
    float bj = bih[j];
    for (int p=0;p<PREP;p++) gi_pre[((size_t)(base+p))*G3H + j] = acc[p]+bj;
  }
  { // ea
    int d = tid & 63; int pg = tid >> 6;   // 6 groups of 64
    float bd = eab[d];
    for (int p=pg; p<PREP; p+=6){
      float acc=0.f;
      #pragma unroll 8
      for (int k=0;k<KBD;k++) acc += eaWT[k*KBD+d]*kbL[p][k];
      ea_pre[((size_t)(base+p))*KBD + d] = tanhf(acc + bd);
    }
  }
}

// ---------------- Sy = tanh(MergeE @ m2W^T + m2b) via MFMA, bf16 out ----------------
__global__ __launch_bounds__(256) void k_sy(
    const float* __restrict__ E, const float* __restrict__ KBE,
    const float* __restrict__ m2W, const float* __restrict__ m2b,
    __hip_bfloat16* __restrict__ Sy) {
  int lane = threadIdx.x & 63;
  int wid  = (blockIdx.x*256 + threadIdx.x) >> 6;
  int r16 = lane & 15, g4 = lane >> 4;
  int kof = g4*8;
  // B frags: m2W rows (out dim) as N, k = ks*32 + kof + c
  sh8 bb[4][4];
  float bias[4];
  #pragma unroll
  for (int nt=0;nt<4;nt++){
    int o = nt*16 + r16;
    bias[nt] = m2b[o];
    #pragma unroll
    for (int ks=0;ks<4;ks++){
      const float* wp = m2W + o*128 + ks*32 + kof;
      sh8 v;
      #pragma unroll
      for (int c=0;c<8;c++) v[c] = f2bs(wp[c]);
      bb[nt][ks]=v;
    }
  }
  int nw = gridDim.x*4;
  for (int tile=wid; tile<NTILE; tile+=nw){
    int v = tile*16 + r16;
    sh8 aa[4];
    const float* ep = E + (size_t)v*EMB + kof;
    const float* kp = KBE + (size_t)v*KBD + kof;
    #pragma unroll
    for (int ks=0;ks<2;ks++){
      sh8 x;
      #pragma unroll
      for (int c=0;c<8;c++) x[c] = f2bs(ep[ks*32+c]);
      aa[ks]=x;
    }
    #pragma unroll
    for (int ks=0;ks<2;ks++){
      sh8 x;
      #pragma unroll
      for (int c=0;c<8;c++) x[c] = f2bs(kp[ks*32+c]);
      aa[2+ks]=x;
    }
    if (v==0){
      sh8 z = {0,0,0,0,0,0,0,0};
      aa[0]=z; aa[1]=z; aa[2]=z; aa[3]=z;
    }
    f32x4 acc[4];
    #pragma unroll
    for (int nt=0;nt<4;nt++){ f32x4 z={0.f,0.f,0.f,0.f}; acc[nt]=z; }
    #pragma unroll
    for (int nt=0;nt<4;nt++)
      #pragma unroll
      for (int ks=0;ks<4;ks++)
        acc[nt] = __builtin_amdgcn_mfma_f32_16x16x32_bf16(aa[ks],bb[nt][ks],acc[nt],0,0,0);
    #pragma unroll
    for (int nt=0;nt<4;nt++){
      #pragma unroll
      for (int r=0;r<4;r++){
        int vv = tile*16 + g4*4 + r;
        Sy[(size_t)vv*OUTD + nt*16 + r16] = __float2bfloat16(tanhf(acc[nt][r] + bias[nt]));
      }
    }
  }
}

// ---------------- the sequential scan: one block per batch row ----------------------
__global__ __launch_bounds__(384) void k_scan(
    const float* __restrict__ gi_pre, const float* __restrict__ ea_pre,
    const __hip_bfloat16* __restrict__ whh_bf, const float* __restrict__ bhh,
    const __hip_bfloat16* __restrict__ uw_bf, const float* __restrict__ ub,
    const float* __restrict__ rmat,
    const __hip_bfloat16* __restrict__ u2_bf, const float* __restrict__ u2b,
    const __hip_bfloat16* __restrict__ m1_bf, const float* __restrict__ m1b,
    __hip_bfloat16* __restrict__ ybf) {
  __shared__ float rmL[NF][KBD];
  __shared__ float mnL[NF][KBD];
  __shared__ float hacL[HH+KBD];   // h[0:128], AC[128:192]
  __shared__ float giL[G3H];
  __shared__ float ghL[G3H];
  __shared__ float eaL[KBD];
  __shared__ float UL[KBD];
  __shared__ float UtL[HH];
  __shared__ float ysumL[OUTD];
  __shared__ float gL[NF], awL[NF], lgL[NF];

  int tid = threadIdx.x;
  int b = blockIdx.x;

  for (int i=tid;i<NF*KBD;i+=384){ rmL[i>>6][i&63]=rmat[i]; mnL[i>>6][i&63]=0.f; }
  if (tid<HH+KBD) hacL[tid]=0.f;
  if (tid<OUTD) ysumL[tid]=0.f;
  float bhh_r = bhh[tid];
  float ub_r  = (tid<KBD)? ub[tid]:0.f;
  float u2b_r = (tid<HH)? u2b[tid]:0.f;
  float m1b_r = (tid<OUTD)? m1b[tid]:0.f;
  __syncthreads();

  const float* gi_b = gi_pre + (size_t)b*TT*G3H;
  const float* ea_b = ea_pre + (size_t)b*TT*KBD;

  for (int t=0;t<TT;t++){
    // phase1: stream gi/ea; gh = Whh . h_old + bhh (all 384 threads)
    giL[tid] = gi_b[t*G3H + tid];
    if (tid<KBD) eaL[tid] = ea_b[t*KBD + tid];
    {
      float acc = bhh_r;
      #pragma unroll
      for (int kb=0;kb<16;kb++){
        sh8 w = *(const sh8*)(whh_bf + ((kb*G3H + tid)<<3));
        float4 h0 = *(const float4*)&hacL[kb*8];
        float4 h1 = *(const float4*)&hacL[kb*8+4];
        acc += b2f(w[0])*h0.x + b2f(w[1])*h0.y + b2f(w[2])*h0.z + b2f(w[3])*h0.w
             + b2f(w[4])*h1.x + b2f(w[5])*h1.y + b2f(w[6])*h1.z + b2f(w[7])*h1.w;
      }
      ghL[tid]=acc;
    }
    __syncthreads();               // A
    // phase2: GRU gates (tid<128)  ||  mem-write gate (tid in [128,288))
    if (tid<HH){
      float r = sigmoidf_(giL[tid]      + ghL[tid]);
      float z = sigmoidf_(giL[HH+tid]   + ghL[HH+tid]);
      float n = tanhf   (giL[2*HH+tid] + r*ghL[2*HH+tid]);
      hacL[tid] = (1.f-z)*n + z*hacL[tid];
    } else if (tid < HH + NF*16){
      int idx = tid - HH;
      int n = idx>>4, l16 = idx&15;
      float p=0.f;
      #pragma unroll
      for (int ii=0;ii<4;ii++){ int d=l16*4+ii; p += mnL[n][d]*(eaL[d]+rmL[n][d]); }
      p += __shfl_xor(p,1,16); p += __shfl_xor(p,2,16);
      p += __shfl_xor(p,4,16); p += __shfl_xor(p,8,16);
      if (l16==0) gL[n]=sigmoidf_(p);
    }
    __syncthreads();               // B
    // phase3: MN update (all)  ||  U = tanh(uW.h + ub) (tid<64)
    for (int oi=tid; oi<NF*KBD; oi+=384){
      int n=oi>>6, d=oi&63;
      float g=gL[n];
      float eav = eaL[d]+rmL[n][d];
      mnL[n][d] += g*(eav - mnL[n][d]);
    }
    if (tid<KBD){
      float acc=ub_r;
      #pragma unroll
      for (int kb=0;kb<16;kb++){
        sh8 w = *(const sh8*)(uw_bf + ((kb*KBD + tid)<<3));
        float4 h0 = *(const float4*)&hacL[kb*8];
        float4 h1 = *(const float4*)&hacL[kb*8+4];
        acc += b2f(w[0])*h0.x + b2f(w[1])*h0.y + b2f(w[2])*h0.z + b2f(w[3])*h0.w
             + b2f(w[4])*h1.x + b2f(w[5])*h1.y + b2f(w[6])*h1.z + b2f(w[7])*h1.w;
      }
      UL[tid]=tanhf(acc);
    }
    __syncthreads();               // C
    // phase4: attention logits
    if (tid<NF*16){
      int n = tid>>4, l16 = tid&15;
      float p=0.f;
      #pragma unroll
      for (int ii=0;ii<4;ii++){ int d=l16*4+ii; p += UL[d]*rmL[n][d]; }
      p += __shfl_xor(p,1,16); p += __shfl_xor(p,2,16);
      p += __shfl_xor(p,4,16); p += __shfl_xor(p,8,16);
      if (l16==0) lgL[n]=p;
    }
    __syncthreads();               // D
    // phase5: softmax over 10
    if (tid==0){
      float m=lgL[0];
      #pragma unroll
      for (int n=1;n<NF;n++) m = fmaxf(m,lgL[n]);
      float s=0.f;
      float e[NF];
      #pragma unroll
      for (int n=0;n<NF;n++){ e[n]=__expf(lgL[n]-m); s+=e[n]; }
      float inv=1.f/s;
      #pragma unroll
      for (int n=0;n<NF;n++) awL[n]=e[n]*inv;
    }
    __syncthreads();               // E
    // phase6: AC
    if (tid<KBD){
      float acc=0.f;
      #pragma unroll
      for (int n=0;n<NF;n++) acc += mnL[n][tid]*awL[n];
      hacL[HH+tid]=acc;
    }
    __syncthreads();               // F
    // phase7: Ut = tanh(u2W . [h;AC] + u2b)
    if (tid<HH){
      float acc=u2b_r;
      #pragma unroll
      for (int kb=0;kb<24;kb++){
        sh8 w = *(const sh8*)(u2_bf + ((kb*HH + tid)<<3));
        float4 h0 = *(const float4*)&hacL[kb*8];
        float4 h1 = *(const float4*)&hacL[kb*8+4];
        acc += b2f(w[0])*h0.x + b2f(w[1])*h0.y + b2f(w[2])*h0.z + b2f(w[3])*h0.w
             + b2f(w[4])*h1.x + b2f(w[5])*h1.y + b2f(w[6])*h1.z + b2f(w[7])*h1.w;
      }
      UtL[tid]=tanhf(acc);
    }
    __syncthreads();               // G
    // phase8: y = tanh(m1W.Ut + m1b); ysum += y   (runs into next phase1)
    if (tid<OUTD){
      float acc=m1b_r;
      #pragma unroll
      for (int kb=0;kb<16;kb++){
        sh8 w = *(const sh8*)(m1_bf + ((kb*OUTD + tid)<<3));
        float4 h0 = *(const float4*)&UtL[kb*8];
        float4 h1 = *(const float4*)&UtL[kb*8+4];
        acc += b2f(w[0])*h0.x + b2f(w[1])*h0.y + b2f(w[2])*h0.z + b2f(w[3])*h0.w
             + b2f(w[4])*h1.x + b2f(w[5])*h1.y + b2f(w[6])*h1.z + b2f(w[7])*h1.w;
      }
      ysumL[tid] += tanhf(acc);
    }
  }
  __syncthreads();
  if (tid<OUTD) ybf[b*OUTD+tid] = __float2bfloat16(ysumL[tid]*(1.0f/TT));
}

// ---------------- final: s = y @ Sy^T, log_softmax (|s|<=64, no max shift) --------
__global__ __launch_bounds__(256) void k_logits(
    const __hip_bfloat16* __restrict__ ybf, const __hip_bfloat16* __restrict__ Sy,
    float* __restrict__ denom, float* __restrict__ out, int pass) {
  int lane = threadIdx.x & 63;
  int w = threadIdx.x >> 6;
  int r16 = lane & 15, g4 = lane >> 4;
  int kof = g4 * 8;
  int tbase = blockIdx.x * 16 + w * 4;
  sh8 b0[4], b1[4];
  #pragma unroll
  for (int i=0;i<4;i++){
    if (tbase + i < NTILE) {
      const __hip_bfloat16* bp = Sy + ((size_t)((tbase+i)*16 + r16))*OUTD + kof;
      b0[i] = *(const sh8*)bp;
      b1[i] = *(const sh8*)(bp + 32);
    } else {
      sh8 z = {0,0,0,0,0,0,0,0};
      b0[i]=z; b1[i]=z;
    }
  }
  int bg0 = blockIdx.y * 4;
  for (int bgi=0; bgi<4; bgi++){
    int bg = bg0 + bgi;
    const __hip_bfloat16* ap = ybf + (bg*16 + r16)*OUTD + kof;
    sh8 a0 = *(const sh8*)ap;
    sh8 a1 = *(const sh8*)(ap+32);
    if (pass == 0){
      float part[4] = {0.f,0.f,0.f,0.f};
      #pragma unroll
      for (int i=0;i<4;i++){
        if (tbase + i < NTILE){
          f32x4 acc = {0.f,0.f,0.f,0.f};
          acc = __builtin_amdgcn_mfma_f32_16x16x32_bf16(a0,b0[i],acc,0,0,0);
          acc = __builtin_amdgcn_mfma_f32_16x16x32_bf16(a1,b1[i],acc,0,0,0);
          #pragma unroll
          for (int r=0;r<4;r++) part[r] += __expf(acc[r]);
        }
      }
      #pragma unroll
      for (int r=0;r<4;r++){
        float p = part[r];
        p += __shfl_xor(p,1,16); p += __shfl_xor(p,2,16);
        p += __shfl_xor(p,4,16); p += __shfl_xor(p,8,16);
        if (r16==0) atomicAdd(&denom[bg*16 + g4*4 + r], p);
      }
    } else {
      float lse[4];
      #pragma unroll
      for (int r=0;r<4;r++) lse[r] = logf(denom[bg*16 + g4*4 + r]);
      #pragma unroll
      for (int i=0;i<4;i++){
        if (tbase + i < NTILE){
          f32x4 acc = {0.f,0.f,0.f,0.f};
          acc = __builtin_amdgcn_mfma_f32_16x16x32_bf16(a0,b0[i],acc,0,0,0);
          acc = __builtin_amdgcn_mfma_f32_16x16x32_bf16(a1,b1[i],acc,0,0,0);
          int vc = (tbase+i)*16 + r16;
          #pragma unroll
          for (int r=0;r<4;r++)
            out[(size_t)(bg*16 + g4*4 + r)*VV + vc] = acc[r] - lse[r];
        }
      }
    }
  }
}

extern "C" void kernel_launch(void* const* d_in, const int* in_sizes, int n_in,
                              void* d_out, int out_size, void* d_ws, size_t ws_size,
                              hipStream_t stream) {
  const int*   X    = (const int*)  d_in[0];
  const float* E    = (const float*)d_in[1];
  const float* KBE  = (const float*)d_in[2];
  const float* rmat = (const float*)d_in[3];
  const float* Wih  = (const float*)d_in[4];
  const float* Whh  = (const float*)d_in[5];
  const float* bih  = (const float*)d_in[6];
  const float* bhh  = (const float*)d_in[7];
  const float* uW   = (const float*)d_in[8];
  const float* ub   = (const float*)d_in[9];
  const float* eaW  = (const float*)d_in[10];
  const float* eab  = (const float*)d_in[11];
  const float* u2W  = (const float*)d_in[12];
  const float* u2b  = (const float*)d_in[13];
  const float* m1W  = (const float*)d_in[14];
  const float* m1b  = (const float*)d_in[15];
  const float* m2W  = (const float*)d_in[16];
  const float* m2b  = (const float*)d_in[17];
  float* outp = (float*)d_out;

  char* p = (char*)d_ws;
  float* WihT   = (float*)p;            p += (size_t)EMB*G3H*4;
  float* eaWT   = (float*)p;            p += (size_t)KBD*KBD*4;
  float* gi_pre = (float*)p;            p += (size_t)BB*TT*G3H*4;
  float* ea_pre = (float*)p;            p += (size_t)BB*TT*KBD*4;
  float* denom  = (float*)p;            p += 1024;
  __hip_bfloat16* whh_bf = (__hip_bfloat16*)p; p += (size_t)16*G3H*8*2;
  __hip_bfloat16* u2_bf  = (__hip_bfloat16*)p; p += (size_t)24*HH*8*2;
  __hip_bfloat16* uw_bf  = (__hip_bfloat16*)p; p += (size_t)16*OUTD*8*2;
  __hip_bfloat16* m1_bf  = (__hip_bfloat16*)p; p += (size_t)16*OUTD*8*2;
  __hip_bfloat16* ybf    = (__hip_bfloat16*)p; p += (size_t)BB*OUTD*2;
  __hip_bfloat16* Sy     = (__hip_bfloat16*)p; p += (size_t)VV*OUTD*2;

  k_trans<<<128,256,0,stream>>>(Whh,Wih,uW,eaW,u2W,m1W, WihT,eaWT,whh_bf,u2_bf,uw_bf,m1_bf);
  k_pre<<<(BB*TT)/PREP,384,0,stream>>>(X,E,KBE,WihT,bih,eaWT,eab,gi_pre,ea_pre);
  k_sy<<<625,256,0,stream>>>(E,KBE,m2W,m2b,Sy);
  k_scan<<<BB,384,0,stream>>>(gi_pre,ea_pre,whh_bf,bhh,uw_bf,ub,rmat,u2_bf,u2b,m1_bf,m1b,ybf);
  hipMemsetAsync(denom, 0, BB*sizeof(float), stream);
  dim3 g1((NTILE + 15)/16, 4, 1);
  k_logits<<<g1,256,0,stream>>>(ybf,Sy,denom,outp,0);
  k_logits<<<g1,256,0,stream>>>(ybf,Sy,denom,outp,1);
}

// Round 3
// 572.162 us; speedup vs baseline: 2.7408x; 1.4360x over previous
//
#include <hip/hip_runtime.h>
#include <hip/hip_bf16.h>
#include <math.h>

#define BB 256
#define TT 50
#define VV 100000
#define EMB 64
#define KBD 64
#define HH 128
#define NF 10
#define OUTD 64
#define G3H 384
#define NTILE 6250   // VV/16

typedef __attribute__((ext_vector_type(8))) short sh8;
typedef __attribute__((ext_vector_type(4))) short sh4;
typedef __attribute__((ext_vector_type(2))) short sh2;
typedef __attribute__((ext_vector_type(4))) float f32x4;

__device__ __forceinline__ float sigm(float x){ return 1.0f/(1.0f+__expf(-x)); }
__device__ __forceinline__ float tanh_(float x){ return 1.0f - 2.0f/(__expf(2.0f*x)+1.0f); }
__device__ __forceinline__ float b2f(short s){ return __uint_as_float(((unsigned)(unsigned short)s)<<16); }
__device__ __forceinline__ short f2bs(float f){ __hip_bfloat16 h=__float2bfloat16(f); return *reinterpret_cast<short*>(&h); }
__device__ __forceinline__ sh8 ldfrag(const float* p){
  float4 a = *(const float4*)p; float4 b = *(const float4*)(p+4);
  sh8 v;
  v[0]=f2bs(a.x); v[1]=f2bs(a.y); v[2]=f2bs(a.z); v[3]=f2bs(a.w);
  v[4]=f2bs(b.x); v[5]=f2bs(b.y); v[6]=f2bs(b.z); v[7]=f2bs(b.w);
  return v;
}

// ---------------- transpose weights for k_pre ----------------
__global__ void k_trans(const float* __restrict__ Wih, const float* __restrict__ eaW,
                        float* __restrict__ WihT, float* __restrict__ eaWT) {
  int stride = gridDim.x*blockDim.x;
  int tid0 = blockIdx.x*blockDim.x + threadIdx.x;
  for (int i=tid0; i<G3H*EMB; i+=stride){ int j=i/EMB, k=i%EMB; WihT[k*G3H+j]=Wih[i]; }
  for (int i=tid0; i<KBD*KBD; i+=stride){ int j=i/KBD, k=i%KBD; eaWT[k*KBD+j]=eaW[i]; }
}

// ---------------- precompute gi[b,t,384] and ea[b,t,64] ----------------
#define PREP 32
__global__ __launch_bounds__(384) void k_pre(
    const int* __restrict__ X, const float* __restrict__ E, const float* __restrict__ KBE,
    const float* __restrict__ WihT, const float* __restrict__ bih,
    const float* __restrict__ eaWT, const float* __restrict__ eab,
    float* __restrict__ gi_pre, float* __restrict__ ea_pre) {
  __shared__ float xeL[PREP][EMB];
  __shared__ float kbL[PREP][KBD];
  int tid = threadIdx.x;
  int base = blockIdx.x * PREP;
  for (int i=tid; i<PREP*EMB; i+=384){
    int p=i>>6, k=i&63; int x = X[base+p];
    xeL[p][k] = x ? E[(size_t)x*EMB+k] : 0.0f;
    kbL[p][k] = x ? KBE[(size_t)x*KBD+k] : 0.0f;
  }
  __syncthreads();
  {
    int j = tid;
    float acc[PREP];
    #pragma unroll
    for (int p=0;p<PREP;p++) acc[p]=0.f;
    for (int k=0;k<EMB;k++){
      float w = WihT[k*G3H+j];
      #pragma unroll
      for (int p=0;p<PREP;p++) acc[p] += w*xeL[p][k];
    }
    float bj = bih[j];
    for (int p=0;p<PREP;p++) gi_pre[((size_t)(base+p))*G3H + j] = acc[p]+bj;
  }
  {
    int d = tid & 63; int pg = tid >> 6;
    float bd = eab[d];
    for (int p=pg; p<PREP; p+=6){
      float acc=0.f;
      #pragma unroll 8
      for (int k=0;k<KBD;k++) acc += eaWT[k*KBD+d]*kbL[p][k];
      ea_pre[((size_t)(base+p))*KBD + d] = tanhf(acc + bd);
    }
  }
}

// ---------------- Sy = tanh(MergeE @ m2W^T + m2b) via MFMA, bf16 out ----------------
__global__ __launch_bounds__(256) void k_sy(
    const float* __restrict__ E, const float* __restrict__ KBE,
    const float* __restrict__ m2W, const float* __restrict__ m2b,
    __hip_bfloat16* __restrict__ Sy) {
  int lane = threadIdx.x & 63;
  int wid  = (blockIdx.x*256 + threadIdx.x) >> 6;
  int r16 = lane & 15, g4 = lane >> 4;
  int kof = g4*8;
  sh8 bb[4][4];
  float bias[4];
  #pragma unroll
  for (int nt=0;nt<4;nt++){
    int o = nt*16 + r16;
    bias[nt] = m2b[o];
    #pragma unroll
    for (int ks=0;ks<4;ks++) bb[nt][ks] = ldfrag(m2W + o*128 + ks*32 + kof);
  }
  int nw = gridDim.x*4;
  for (int tile=wid; tile<NTILE; tile+=nw){
    int v = tile*16 + r16;
    sh8 aa[4];
    const float* ep = E + (size_t)v*EMB + kof;
    const float* kp = KBE + (size_t)v*KBD + kof;
    aa[0] = ldfrag(ep); aa[1] = ldfrag(ep+32);
    aa[2] = ldfrag(kp); aa[3] = ldfrag(kp+32);
    if (v==0){
      sh8 z = {0,0,0,0,0,0,0,0};
      aa[0]=z; aa[1]=z; aa[2]=z; aa[3]=z;
    }
    f32x4 acc[4];
    #pragma unroll
    for (int nt=0;nt<4;nt++){ f32x4 z={0.f,0.f,0.f,0.f}; acc[nt]=z; }
    #pragma unroll
    for (int nt=0;nt<4;nt++)
      #pragma unroll
      for (int ks=0;ks<4;ks++)
        acc[nt] = __builtin_amdgcn_mfma_f32_16x16x32_bf16(aa[ks],bb[nt][ks],acc[nt],0,0,0);
    #pragma unroll
    for (int nt=0;nt<4;nt++){
      #pragma unroll
      for (int r=0;r<4;r++){
        int vv = tile*16 + g4*4 + r;
        Sy[(size_t)vv*OUTD + nt*16 + r16] = __float2bfloat16(tanhf(acc[nt][r] + bias[nt]));
      }
    }
  }
}

// ---------------- the scan: 16 rows/block, 8 waves, all-MFMA ----------------------
__global__ __launch_bounds__(512) void k_scan(
    const float* __restrict__ gi_pre, const float* __restrict__ ea_pre,
    const float* __restrict__ Whh, const float* __restrict__ bhh,
    const float* __restrict__ uW, const float* __restrict__ ub,
    const float* __restrict__ rmat,
    const float* __restrict__ u2W, const float* __restrict__ u2b,
    const float* __restrict__ m1W, const float* __restrict__ m1b,
    __hip_bfloat16* __restrict__ ybf) {
  // LDS state
  __shared__ __hip_bfloat16 hcat[2][16][216];   // [buf][row][k]: k<128 = h, 128..191 = AC
  __shared__ __hip_bfloat16 u_buf[16][72];
  __shared__ __hip_bfloat16 ut_buf[16][136];
  __shared__ float mn[16*680];                  // [row][n][d] strides 680/68
  __shared__ float ea_l[16*68];
  __shared__ float rm_l[NF*68];
  __shared__ float aw_l[16*16];
  __shared__ float g_l[16*12];

  const int tid = threadIdx.x;
  const int w = tid>>6, l = tid&63, r16 = l&15, g4 = l>>4;
  const int b0 = blockIdx.x*16;

  for (int i=tid;i<16*680;i+=512) mn[i]=0.f;
  for (int i=tid;i<2*16*216;i+=512) ((short*)hcat)[i]=0;
  for (int i=tid;i<NF*KBD;i+=512) rm_l[(i>>6)*68 + (i&63)] = rmat[i];
  for (int i=tid;i<16*KBD;i+=512)
    ea_l[(i>>6)*68+(i&63)] = ea_pre[(size_t)(b0+(i>>6))*TT*KBD + (i&63)];

  // ---- persistent weight fragments (A-operands, m = weight-out dim)
  sh8 whhF[3][4];
  #pragma unroll
  for (int i=0;i<3;i++){
    int jb = (i*8+w)*16;
    #pragma unroll
    for (int f=0;f<4;f++) whhF[i][f] = ldfrag(Whh + (size_t)(jb+r16)*HH + f*32 + g4*8);
  }
  sh8 u2F[6];
  #pragma unroll
  for (int f=0;f<6;f++) u2F[f] = ldfrag(u2W + (size_t)(w*16+r16)*(HH+KBD) + f*32 + g4*8);
  sh8 wF4[4];  // uW for waves 0-3, m1W for waves 4-7
  {
    const float* wsrc = (w<4) ? (uW + (size_t)(w*16+r16)*HH) : (m1W + (size_t)((w-4)*16+r16)*HH);
    #pragma unroll
    for (int f=0;f<4;f++) wF4[f] = ldfrag(wsrc + f*32 + g4*8);
  }
  sh8 rmF[2];
  #pragma unroll
  for (int f=0;f<2;f++){
    sh8 z = {0,0,0,0,0,0,0,0};
    if (r16 < NF) z = ldfrag(rmat + (size_t)r16*KBD + f*32 + g4*8);
    rmF[f] = z;
  }
  float4 bhh_f[3];
  #pragma unroll
  for (int i=0;i<3;i++) bhh_f[i] = *(const float4*)(bhh + (i*8+w)*16 + g4*4);
  float4 b4_f = (w<4) ? *(const float4*)(ub + w*16+g4*4) : *(const float4*)(m1b + (w-4)*16+g4*4);
  float4 u2b_f = *(const float4*)(u2b + w*16+g4*4);

  float h_old[4] = {0.f,0.f,0.f,0.f};
  float ysum[4] = {0.f,0.f,0.f,0.f};

  const float* gi_row = gi_pre + (size_t)(b0+r16)*TT*G3H;
  float4 gi_f[3];
  #pragma unroll
  for (int i=0;i<3;i++) gi_f[i] = *(const float4*)(gi_row + (i*8+w)*16 + g4*4);

  __syncthreads();

  int cur = 0;
  for (int t=0;t<TT;t++){
    const int nb = cur^1;
    // ---- phase A: gh = Whh.h + bhh (MFMA), GRU update, write h_new bf16
    {
      sh8 hb[4];
      #pragma unroll
      for (int f=0;f<4;f++) hb[f] = *(const sh8*)&hcat[cur][r16][f*32+g4*8];
      f32x4 acc0={0.f,0.f,0.f,0.f}, acc1=acc0, acc2=acc0;
      #pragma unroll
      for (int f=0;f<4;f++){
        acc0 = __builtin_amdgcn_mfma_f32_16x16x32_bf16(whhF[0][f], hb[f], acc0,0,0,0);
        acc1 = __builtin_amdgcn_mfma_f32_16x16x32_bf16(whhF[1][f], hb[f], acc1,0,0,0);
        acc2 = __builtin_amdgcn_mfma_f32_16x16x32_bf16(whhF[2][f], hb[f], acc2,0,0,0);
      }
      sh4 hp;
      #pragma unroll
      for (int r=0;r<4;r++){
        float rr = sigm(gi_f[0][r] + acc0[r] + bhh_f[0][r]);
        float zz = sigm(gi_f[1][r] + acc1[r] + bhh_f[1][r]);
        float nn = tanh_(gi_f[2][r] + rr*(acc2[r] + bhh_f[2][r]));
        h_old[r] = (1.f-zz)*nn + zz*h_old[r];
        hp[r] = f2bs(h_old[r]);
      }
      *(sh4*)&hcat[nb][r16][w*16+g4*4] = hp;
    }
    __syncthreads();  // 1
    // ---- phase B: U (waves 0-3, MFMA) || memory-write gate (waves 4-7)
    if (w<4){
      sh8 hb2[4];
      #pragma unroll
      for (int f=0;f<4;f++) hb2[f] = *(const sh8*)&hcat[nb][r16][f*32+g4*8];
      f32x4 au={0.f,0.f,0.f,0.f};
      #pragma unroll
      for (int f=0;f<4;f++) au = __builtin_amdgcn_mfma_f32_16x16x32_bf16(wF4[f], hb2[f], au,0,0,0);
      sh4 up;
      #pragma unroll
      for (int r=0;r<4;r++) up[r] = f2bs(tanh_(au[r] + b4_f[r]));
      *(sh4*)&u_buf[r16][w*16+g4*4] = up;
    } else {
      int p = (w-4)*64 + l;
      if (p < 16*NF){
        int row = p/NF, n = p - row*NF;
        float accg = 0.f;
        #pragma unroll
        for (int dd=0;dd<64;dd+=4){
          float4 m = *(const float4*)&mn[row*680+n*68+dd];
          float4 e = *(const float4*)&ea_l[row*68+dd];
          float4 rv= *(const float4*)&rm_l[n*68+dd];
          accg += m.x*(e.x+rv.x)+m.y*(e.y+rv.y)+m.z*(e.z+rv.z)+m.w*(e.w+rv.w);
        }
        g_l[row*12+n] = sigm(accg);
      }
    }
    __syncthreads();  // 2
    // ---- phase C: attention logits+softmax (wave 0) || MN update (waves 1-7)
    if (w==0){
      sh8 ubf[2];
      #pragma unroll
      for (int f=0;f<2;f++) ubf[f] = *(const sh8*)&u_buf[r16][f*32+g4*8];
      f32x4 al={0.f,0.f,0.f,0.f};
      #pragma unroll
      for (int f=0;f<2;f++) al = __builtin_amdgcn_mfma_f32_16x16x32_bf16(rmF[f], ubf[f], al,0,0,0);
      float lm = -1e30f;
      #pragma unroll
      for (int r=0;r<4;r++){ int m = g4*4+r; if (m<NF) lm = fmaxf(lm, al[r]); }
      lm = fmaxf(lm, __shfl_xor(lm,16));
      lm = fmaxf(lm, __shfl_xor(lm,32));
      float ev[4]; float s=0.f;
      #pragma unroll
      for (int r=0;r<4;r++){ int m = g4*4+r; ev[r] = (m<NF)? __expf(al[r]-lm):0.f; s += ev[r]; }
      s += __shfl_xor(s,16); s += __shfl_xor(s,32);
      float inv = 1.f/s;
      #pragma unroll
      for (int r=0;r<4;r++){ int m = g4*4+r; if (m<NF) aw_l[r16*16+m] = ev[r]*inv; }
    } else {
      int base = (w-1)*64 + l;
      for (int p2=base; p2<16*NF*32; p2+=448){
        int row = p2/(NF*32); int rest = p2 - row*(NF*32); int n = rest>>5; int d2 = (rest&31)<<1;
        int idx = row*680+n*68+d2;
        float2 m = *(const float2*)&mn[idx];
        float2 e = *(const float2*)&ea_l[row*68+d2];
        float2 rv= *(const float2*)&rm_l[n*68+d2];
        float g = g_l[row*12+n];
        m.x += g*((e.x+rv.x)-m.x);
        m.y += g*((e.y+rv.y)-m.y);
        *(float2*)&mn[idx] = m;
      }
    }
    __syncthreads();  // 3
    // ---- phase D: AC = sum_n MN*aw -> hcat[nb] k=128..191 (all threads)
    {
      int row = tid>>5, d2 = (tid&31)<<1;
      float ax=0.f, ay=0.f;
      #pragma unroll
      for (int n=0;n<NF;n++){
        float2 m = *(const float2*)&mn[row*680+n*68+d2];
        float aw = aw_l[row*16+n];
        ax += m.x*aw; ay += m.y*aw;
      }
      sh2 ap; ap[0]=f2bs(ax); ap[1]=f2bs(ay);
      *(sh2*)&hcat[nb][row][HH+d2] = ap;
    }
    __syncthreads();  // 4
    // ---- phase E: Ut = tanh(u2.[h;AC]) (all 8 waves, MFMA)
    {
      sh8 cb[6];
      #pragma unroll
      for (int f=0;f<6;f++) cb[f] = *(const sh8*)&hcat[nb][r16][f*32+g4*8];
      f32x4 at={0.f,0.f,0.f,0.f};
      #pragma unroll
      for (int f=0;f<6;f++) at = __builtin_amdgcn_mfma_f32_16x16x32_bf16(u2F[f], cb[f], at,0,0,0);
      sh4 tp;
      #pragma unroll
      for (int r=0;r<4;r++) tp[r] = f2bs(tanh_(at[r] + u2b_f[r]));
      *(sh4*)&ut_buf[r16][w*16+g4*4] = tp;
    }
    __syncthreads();  // 5
    // ---- phase F: y (waves 4-7, MFMA) + prefetch t+1 (no trailing barrier)
    if (w>=4){
      sh8 tb[4];
      #pragma unroll
      for (int f=0;f<4;f++) tb[f] = *(const sh8*)&ut_buf[r16][f*32+g4*8];
      f32x4 ay={0.f,0.f,0.f,0.f};
      #pragma unroll
      for (int f=0;f<4;f++) ay = __builtin_amdgcn_mfma_f32_16x16x32_bf16(wF4[f], tb[f], ay,0,0,0);
      #pragma unroll
      for (int r=0;r<4;r++) ysum[r] += tanh_(ay[r] + b4_f[r]);
    }
    int tn = (t+1<TT)? t+1 : t;
    #pragma unroll
    for (int i=0;i<3;i++) gi_f[i] = *(const float4*)(gi_row + tn*G3H + (i*8+w)*16 + g4*4);
    for (int i=tid;i<16*KBD;i+=512){
      int rw=i>>6, d=i&63;
      ea_l[rw*68+d] = ea_pre[(size_t)(b0+rw)*TT*KBD + tn*KBD + d];
    }
    cur ^= 1;
  }
  if (w>=4){
    #pragma unroll
    for (int r=0;r<4;r++)
      ybf[(size_t)(b0+r16)*OUTD + (w-4)*16 + g4*4 + r] = __float2bfloat16(ysum[r]*(1.0f/TT));
  }
}

// ---------------- final: s = y @ Sy^T, log_softmax (|s|<=64, no max shift) --------
__global__ __launch_bounds__(256) void k_logits(
    const __hip_bfloat16* __restrict__ ybf, const __hip_bfloat16* __restrict__ Sy,
    float* __restrict__ denom, float* __restrict__ out, int pass) {
  int lane = threadIdx.x & 63;
  int w = threadIdx.x >> 6;
  int r16 = lane & 15, g4 = lane >> 4;
  int kof = g4 * 8;
  int tbase = blockIdx.x * 16 + w * 4;
  sh8 b0[4], b1[4];
  #pragma unroll
  for (int i=0;i<4;i++){
    if (tbase + i < NTILE) {
      const __hip_bfloat16* bp = Sy + ((size_t)((tbase+i)*16 + r16))*OUTD + kof;
      b0[i] = *(const sh8*)bp;
      b1[i] = *(const sh8*)(bp + 32);
    } else {
      sh8 z = {0,0,0,0,0,0,0,0};
      b0[i]=z; b1[i]=z;
    }
  }
  int bg0 = blockIdx.y * 4;
  for (int bgi=0; bgi<4; bgi++){
    int bg = bg0 + bgi;
    const __hip_bfloat16* ap = ybf + (bg*16 + r16)*OUTD + kof;
    sh8 a0 = *(const sh8*)ap;
    sh8 a1 = *(const sh8*)(ap+32);
    if (pass == 0){
      float part[4] = {0.f,0.f,0.f,0.f};
      #pragma unroll
      for (int i=0;i<4;i++){
        if (tbase + i < NTILE){
          f32x4 acc = {0.f,0.f,0.f,0.f};
          acc = __builtin_amdgcn_mfma_f32_16x16x32_bf16(a0,b0[i],acc,0,0,0);
          acc = __builtin_amdgcn_mfma_f32_16x16x32_bf16(a1,b1[i],acc,0,0,0);
          #pragma unroll
          for (int r=0;r<4;r++) part[r] += __expf(acc[r]);
        }
      }
      #pragma unroll
      for (int r=0;r<4;r++){
        float p = part[r];
        p += __shfl_xor(p,1,16); p += __shfl_xor(p,2,16);
        p += __shfl_xor(p,4,16); p += __shfl_xor(p,8,16);
        if (r16==0) atomicAdd(&denom[bg*16 + g4*4 + r], p);
      }
    } else {
      float lse[4];
      #pragma unroll
      for (int r=0;r<4;r++) lse[r] = logf(denom[bg*16 + g4*4 + r]);
      #pragma unroll
      for (int i=0;i<4;i++){
        if (tbase + i < NTILE){
          f32x4 acc = {0.f,0.f,0.f,0.f};
          acc = __builtin_amdgcn_mfma_f32_16x16x32_bf16(a0,b0[i],acc,0,0,0);
          acc = __builtin_amdgcn_mfma_f32_16x16x32_bf16(a1,b1[i],acc,0,0,0);
          int vc = (tbase+i)*16 + r16;
          #pragma unroll
          for (int r=0;r<4;r++)
            out[(size_t)(bg*16 + g4*4 + r)*VV + vc] = acc[r] - lse[r];
        }
      }
    }
  }
}

extern "C" void kernel_launch(void* const* d_in, const int* in_sizes, int n_in,
                              void* d_out, int out_size, void* d_ws, size_t ws_size,
                              hipStream_t stream) {
  const int*   X    = (const int*)  d_in[0];
  const float* E    = (const float*)d_in[1];
  const float* KBE  = (const float*)d_in[2];
  const float* rmat = (const float*)d_in[3];
  const float* Wih  = (const float*)d_in[4];
  const float* Whh  = (const float*)d_in[5];
  const float* bih  = (const float*)d_in[6];
  const float* bhh  = (const float*)d_in[7];
  const float* uW   = (const float*)d_in[8];
  const float* ub   = (const float*)d_in[9];
  const float* eaW  = (const float*)d_in[10];
  const float* eab  = (const float*)d_in[11];
  const float* u2W  = (const float*)d_in[12];
  const float* u2b  = (const float*)d_in[13];
  const float* m1W  = (const float*)d_in[14];
  const float* m1b  = (const float*)d_in[15];
  const float* m2W  = (const float*)d_in[16];
  const float* m2b  = (const float*)d_in[17];
  float* outp = (float*)d_out;

  char* p = (char*)d_ws;
  float* WihT   = (float*)p;            p += (size_t)EMB*G3H*4;
  float* eaWT   = (float*)p;            p += (size_t)KBD*KBD*4;
  float* gi_pre = (float*)p;            p += (size_t)BB*TT*G3H*4;
  float* ea_pre = (float*)p;            p += (size_t)BB*TT*KBD*4;
  float* denom  = (float*)p;            p += 1024;
  __hip_bfloat16* ybf    = (__hip_bfloat16*)p; p += (size_t)BB*OUTD*2;
  __hip_bfloat16* Sy     = (__hip_bfloat16*)p; p += (size_t)VV*OUTD*2;

  k_trans<<<64,256,0,stream>>>(Wih,eaW,WihT,eaWT);
  k_pre<<<(BB*TT)/PREP,384,0,stream>>>(X,E,KBE,WihT,bih,eaWT,eab,gi_pre,ea_pre);
  k_sy<<<625,256,0,stream>>>(E,KBE,m2W,m2b,Sy);
  k_scan<<<16,512,0,stream>>>(gi_pre,ea_pre,Whh,bhh,uW,ub,rmat,u2W,u2b,m1W,m1b,ybf);
  hipMemsetAsync(denom, 0, BB*sizeof(float), stream);
  dim3 g1((NTILE + 15)/16, 4, 1);
  k_logits<<<g1,256,0,stream>>>(ybf,Sy,denom,outp,0);
  k_logits<<<g1,256,0,stream>>>(ybf,Sy,denom,outp,1);
}

// Round 4
// 332.646 us; speedup vs baseline: 4.7143x; 1.7200x over previous
//
#include <hip/hip_runtime.h>
#include <hip/hip_bf16.h>
#include <math.h>

#define BB 256
#define TT 50
#define VV 100000
#define EMB 64
#define KBD 64
#define HH 128
#define NF 10
#define OUTD 64
#define G3H 384
#define NTILE 6250   // VV/16
#define DSTR 16      // denom stride (floats)

typedef __attribute__((ext_vector_type(8))) short sh8;
typedef __attribute__((ext_vector_type(4))) short sh4;
typedef __attribute__((ext_vector_type(2))) short sh2;
typedef __attribute__((ext_vector_type(4))) float f32x4;

__device__ __forceinline__ float frcp(float x){ return __builtin_amdgcn_rcpf(x); }
__device__ __forceinline__ float sigm(float x){ return frcp(1.0f+__expf(-x)); }
__device__ __forceinline__ float tanhf_(float x){ return 1.0f - 2.0f*frcp(__expf(2.0f*x)+1.0f); }
__device__ __forceinline__ short f2bs(float f){ __hip_bfloat16 h=__float2bfloat16(f); return *reinterpret_cast<short*>(&h); }
__device__ __forceinline__ sh8 ldfrag(const float* p){
  float4 a = *(const float4*)p; float4 b = *(const float4*)(p+4);
  sh8 v;
  v[0]=f2bs(a.x); v[1]=f2bs(a.y); v[2]=f2bs(a.z); v[3]=f2bs(a.w);
  v[4]=f2bs(b.x); v[5]=f2bs(b.y); v[6]=f2bs(b.z); v[7]=f2bs(b.w);
  return v;
}

// ---------------- transpose weights for k_pre ----------------
__global__ void k_trans(const float* __restrict__ Wih, const float* __restrict__ eaW,
                        float* __restrict__ WihT, float* __restrict__ eaWT) {
  int stride = gridDim.x*blockDim.x;
  int tid0 = blockIdx.x*blockDim.x + threadIdx.x;
  for (int i=tid0; i<G3H*EMB; i+=stride){ int j=i/EMB, k=i%EMB; WihT[k*G3H+j]=Wih[i]; }
  for (int i=tid0; i<KBD*KBD; i+=stride){ int j=i/KBD, k=i%KBD; eaWT[k*KBD+j]=eaW[i]; }
}

// ---------------- precompute gi[b,t,384] (with bih + bhh(r,z) folded) and ea ----------
#define PREP 32
__global__ __launch_bounds__(384) void k_pre(
    const int* __restrict__ X, const float* __restrict__ E, const float* __restrict__ KBE,
    const float* __restrict__ WihT, const float* __restrict__ bih, const float* __restrict__ bhh,
    const float* __restrict__ eaWT, const float* __restrict__ eab,
    float* __restrict__ gi_pre, float* __restrict__ ea_pre) {
  __shared__ float xeL[PREP][EMB];
  __shared__ float kbL[PREP][KBD];
  int tid = threadIdx.x;
  int base = blockIdx.x * PREP;
  for (int i=tid; i<PREP*EMB; i+=384){
    int p=i>>6, k=i&63; int x = X[base+p];
    xeL[p][k] = x ? E[(size_t)x*EMB+k] : 0.0f;
    kbL[p][k] = x ? KBE[(size_t)x*KBD+k] : 0.0f;
  }
  __syncthreads();
  {
    int j = tid;
    float acc[PREP];
    #pragma unroll
    for (int p=0;p<PREP;p++) acc[p]=0.f;
    for (int k=0;k<EMB;k++){
      float w = WihT[k*G3H+j];
      #pragma unroll
      for (int p=0;p<PREP;p++) acc[p] += w*xeL[p][k];
    }
    float bj = bih[j] + (j < 2*HH ? bhh[j] : 0.0f);
    for (int p=0;p<PREP;p++) gi_pre[((size_t)(base+p))*G3H + j] = acc[p]+bj;
  }
  {
    int d = tid & 63; int pg = tid >> 6;
    float bd = eab[d];
    for (int p=pg; p<PREP; p+=6){
      float acc=0.f;
      #pragma unroll 8
      for (int k=0;k<KBD;k++) acc += eaWT[k*KBD+d]*kbL[p][k];
      ea_pre[((size_t)(base+p))*KBD + d] = tanhf(acc + bd);
    }
  }
}

// ========== fused: blocks 0..15 = scan (16 rows each); blocks 16..640 = Sy ==========
__global__ __launch_bounds__(512,2) void k_scan(
    const float* __restrict__ gi_pre, const float* __restrict__ ea_pre,
    const float* __restrict__ Whh, const float* __restrict__ bhh,
    const float* __restrict__ uW, const float* __restrict__ ub,
    const float* __restrict__ rmat,
    const float* __restrict__ u2W, const float* __restrict__ u2b,
    const float* __restrict__ m1W, const float* __restrict__ m1b,
    __hip_bfloat16* __restrict__ ybf,
    const float* __restrict__ E, const float* __restrict__ KBE,
    const float* __restrict__ m2W, const float* __restrict__ m2b,
    __hip_bfloat16* __restrict__ Sy) {
  __shared__ __hip_bfloat16 hcat[2][16][216];   // h[0:128], AC[128:192]
  __shared__ __hip_bfloat16 u_sh[16][88];
  __shared__ __hip_bfloat16 ut_sh[16][152];
  __shared__ float aw_sh[8][16][12];
  __shared__ float gsum[16][12];
  __shared__ float ubL[64]; __shared__ float u2bL[128]; __shared__ float m1bL[64];

  const int tid = threadIdx.x;
  const int w = tid>>6, l = tid&63, r16 = l&15, g4 = l>>4;

  if (blockIdx.x >= 16) {
    // ---------------- Sy path ----------------
    int kof = g4*8;
    sh8 bbf[4][4];
    float bias[4];
    #pragma unroll
    for (int nt=0;nt<4;nt++){
      int o = nt*16 + r16;
      bias[nt] = m2b[o];
      #pragma unroll
      for (int ks=0;ks<4;ks++) bbf[nt][ks] = ldfrag(m2W + o*128 + ks*32 + kof);
    }
    int wid = (blockIdx.x-16)*8 + w;
    for (int tile=wid; tile<NTILE; tile+=5000){
      int v = tile*16 + r16;
      sh8 aa[4];
      const float* ep = E + (size_t)v*EMB + kof;
      const float* kp = KBE + (size_t)v*KBD + kof;
      aa[0] = ldfrag(ep); aa[1] = ldfrag(ep+32);
      aa[2] = ldfrag(kp); aa[3] = ldfrag(kp+32);
      if (v==0){ sh8 z={0,0,0,0,0,0,0,0}; aa[0]=z;aa[1]=z;aa[2]=z;aa[3]=z; }
      f32x4 acc[4];
      #pragma unroll
      for (int nt=0;nt<4;nt++){ f32x4 z={0.f,0.f,0.f,0.f}; acc[nt]=z; }
      #pragma unroll
      for (int nt=0;nt<4;nt++)
        #pragma unroll
        for (int ks=0;ks<4;ks++)
          acc[nt] = __builtin_amdgcn_mfma_f32_16x16x32_bf16(aa[ks],bbf[nt][ks],acc[nt],0,0,0);
      #pragma unroll
      for (int nt=0;nt<4;nt++){
        #pragma unroll
        for (int r=0;r<4;r++){
          int vv = tile*16 + g4*4 + r;
          Sy[(size_t)vv*OUTD + nt*16 + r16] = __float2bfloat16(tanhf(acc[nt][r] + bias[nt]));
        }
      }
    }
    return;
  }

  // ---------------- scan path ----------------
  const int b0 = blockIdx.x*16;
  const int q = w & 3;
  const int d0 = w*8 + g4*2;

  for (int i=tid;i<2*16*216;i+=512) ((short*)hcat)[i]=0;
  if (tid<192) ((float*)gsum)[tid]=0.f;
  if (tid<64) ubL[tid]=ub[tid];
  else if (tid<128) m1bL[tid-64]=m1b[tid-64];
  else if (tid<256) u2bL[tid-128]=u2b[tid-128];

  // persistent weight fragments
  sh8 whhF[3][4];
  #pragma unroll
  for (int i=0;i<3;i++)
    #pragma unroll
    for (int f=0;f<4;f++)
      whhF[i][f] = ldfrag(Whh + (size_t)((i*8+w)*16 + r16)*HH + f*32 + g4*8);
  sh8 u2F[6];
  #pragma unroll
  for (int f=0;f<6;f++) u2F[f] = ldfrag(u2W + (size_t)(w*16+r16)*(HH+KBD) + f*32 + g4*8);
  sh8 uwF[4], m1F[4];
  #pragma unroll
  for (int f=0;f<4;f++){
    uwF[f] = ldfrag(uW  + (size_t)(q*16+r16)*HH + f*32 + g4*8);
    m1F[f] = ldfrag(m1W + (size_t)(q*16+r16)*HH + f*32 + g4*8);
  }
  sh8 rmF[2];
  #pragma unroll
  for (int f=0;f<2;f++){
    sh8 z = {0,0,0,0,0,0,0,0};
    if (r16 < NF) z = ldfrag(rmat + (size_t)r16*KBD + f*32 + g4*8);
    rmF[f] = z;
  }
  float rmA[NF], rmB[NF], mnA[NF], mnB[NF];
  #pragma unroll
  for (int n=0;n<NF;n++){
    rmA[n] = rmat[n*KBD + d0]; rmB[n] = rmat[n*KBD + d0 + 1];
    mnA[n] = 0.f; mnB[n] = 0.f;
  }
  float4 bhn = *(const float4*)(bhh + 2*HH + w*16 + g4*4);
  float h_old[4] = {0.f,0.f,0.f,0.f};
  float ysum[4] = {0.f,0.f,0.f,0.f};

  const float* gi_row = gi_pre + (size_t)(b0+r16)*TT*G3H;
  const float* ea_row = ea_pre + (size_t)(b0+r16)*TT*KBD;
  float4 gi0 = *(const float4*)(gi_row + (0*8+w)*16 + g4*4);
  float4 gi1 = *(const float4*)(gi_row + (1*8+w)*16 + g4*4);
  float4 gi2 = *(const float4*)(gi_row + (2*8+w)*16 + g4*4);
  float2 eaR = *(const float2*)(ea_row + d0);

  __syncthreads();

  int cur = 0;
  for (int t=0;t<TT;t++){
    const int nb = cur^1;
    // ---- P1: gh MFMA + GRU -> h_new; gate partials -> gsum (ds_add)
    {
      sh8 hb[4];
      #pragma unroll
      for (int f=0;f<4;f++) hb[f] = *(const sh8*)&hcat[cur][r16][f*32+g4*8];
      f32x4 a0={0.f,0.f,0.f,0.f}, a1=a0, a2=a0;
      #pragma unroll
      for (int f=0;f<4;f++){
        a0 = __builtin_amdgcn_mfma_f32_16x16x32_bf16(whhF[0][f], hb[f], a0,0,0,0);
        a1 = __builtin_amdgcn_mfma_f32_16x16x32_bf16(whhF[1][f], hb[f], a1,0,0,0);
        a2 = __builtin_amdgcn_mfma_f32_16x16x32_bf16(whhF[2][f], hb[f], a2,0,0,0);
      }
      sh4 hp;
      #pragma unroll
      for (int r=0;r<4;r++){
        float rr = sigm(gi0[r] + a0[r]);
        float zz = sigm(gi1[r] + a1[r]);
        float nn = tanhf_(gi2[r] + rr*(a2[r] + bhn[r]));
        h_old[r] = (1.f-zz)*nn + zz*h_old[r];
        hp[r] = f2bs(h_old[r]);
      }
      *(sh4*)&hcat[nb][r16][w*16+g4*4] = hp;
      // gate partial over this lane's 2 d-values (old MN)
      float pn[NF];
      #pragma unroll
      for (int n=0;n<NF;n++)
        pn[n] = mnA[n]*(eaR.x + rmA[n]) + mnB[n]*(eaR.y + rmB[n]);
      #pragma unroll
      for (int n=0;n<NF;n++){
        pn[n] += __shfl_xor(pn[n],16);
        pn[n] += __shfl_xor(pn[n],32);
      }
      if (g4==0){
        #pragma unroll
        for (int n=0;n<NF;n++) atomicAdd(&gsum[r16][n], pn[n]);
      }
    }
    __syncthreads();  // b1
    // ---- P2a: U = tanh(uW.h_new + ub) (waves 0-3)
    if (w<4){
      sh8 hb2[4];
      #pragma unroll
      for (int f=0;f<4;f++) hb2[f] = *(const sh8*)&hcat[nb][r16][f*32+g4*8];
      f32x4 au={0.f,0.f,0.f,0.f};
      #pragma unroll
      for (int f=0;f<4;f++) au = __builtin_amdgcn_mfma_f32_16x16x32_bf16(uwF[f], hb2[f], au,0,0,0);
      float4 ubv = *(const float4*)&ubL[w*16+g4*4];
      sh4 up;
      #pragma unroll
      for (int r=0;r<4;r++) up[r] = f2bs(tanhf_(au[r] + ubv[r]));
      *(sh4*)&u_sh[r16][w*16+g4*4] = up;
    }
    __syncthreads();  // b2
    // ---- P2b: attn + softmax + g + MN update + AC (all waves, in-wave)
    {
      sh8 uf[2];
      #pragma unroll
      for (int f=0;f<2;f++) uf[f] = *(const sh8*)&u_sh[r16][f*32+g4*8];
      f32x4 al={0.f,0.f,0.f,0.f};
      #pragma unroll
      for (int f=0;f<2;f++) al = __builtin_amdgcn_mfma_f32_16x16x32_bf16(rmF[f], uf[f], al,0,0,0);
      float mx = -1e30f;
      #pragma unroll
      for (int r=0;r<4;r++){ if (g4*4+r < NF) mx = fmaxf(mx, al[r]); }
      mx = fmaxf(mx, __shfl_xor(mx,16));
      mx = fmaxf(mx, __shfl_xor(mx,32));
      float ev[4]; float s=0.f;
      #pragma unroll
      for (int r=0;r<4;r++){ ev[r] = (g4*4+r < NF) ? __expf(al[r]-mx) : 0.f; s += ev[r]; }
      s += __shfl_xor(s,16); s += __shfl_xor(s,32);
      float inv = frcp(s);
      if (g4<3){
        f32x4 av = {ev[0]*inv, ev[1]*inv, ev[2]*inv, ev[3]*inv};
        *(f32x4*)&aw_sh[w][r16][g4*4] = av;
      }
      f32x4 gs0 = *(const f32x4*)&gsum[r16][0];
      f32x4 gs1 = *(const f32x4*)&gsum[r16][4];
      f32x4 gs2 = *(const f32x4*)&gsum[r16][8];
      f32x4 aw0 = *(const f32x4*)&aw_sh[w][r16][0];
      f32x4 aw1 = *(const f32x4*)&aw_sh[w][r16][4];
      f32x4 aw2 = *(const f32x4*)&aw_sh[w][r16][8];
      float ac0=0.f, ac1=0.f;
      #pragma unroll
      for (int n=0;n<NF;n++){
        float gsv = (n<4)? gs0[n] : (n<8)? gs1[n-4] : gs2[n-8];
        float awn = (n<4)? aw0[n] : (n<8)? aw1[n-4] : aw2[n-8];
        float g = sigm(gsv);
        mnA[n] += g*((eaR.x + rmA[n]) - mnA[n]);
        mnB[n] += g*((eaR.y + rmB[n]) - mnB[n]);
        ac0 += mnA[n]*awn;
        ac1 += mnB[n]*awn;
      }
      sh2 acp; acp[0]=f2bs(ac0); acp[1]=f2bs(ac1);
      *(sh2*)&hcat[nb][r16][HH + d0] = acp;
      // prefetch t+1
      int tn = (t+1<TT)? t+1 : t;
      gi0 = *(const float4*)(gi_row + tn*G3H + (0*8+w)*16 + g4*4);
      gi1 = *(const float4*)(gi_row + tn*G3H + (1*8+w)*16 + g4*4);
      gi2 = *(const float4*)(gi_row + tn*G3H + (2*8+w)*16 + g4*4);
      eaR = *(const float2*)(ea_row + tn*KBD + d0);
    }
    __syncthreads();  // b3
    // ---- P3: Ut = tanh(u2.[h;AC] + u2b); zero gsum
    {
      sh8 cb[6];
      #pragma unroll
      for (int f=0;f<6;f++) cb[f] = *(const sh8*)&hcat[nb][r16][f*32+g4*8];
      f32x4 at={0.f,0.f,0.f,0.f};
      #pragma unroll
      for (int f=0;f<6;f++) at = __builtin_amdgcn_mfma_f32_16x16x32_bf16(u2F[f], cb[f], at,0,0,0);
      float4 u2bv = *(const float4*)&u2bL[w*16+g4*4];
      sh4 tp;
      #pragma unroll
      for (int r=0;r<4;r++) tp[r] = f2bs(tanhf_(at[r] + u2bv[r]));
      *(sh4*)&ut_sh[r16][w*16+g4*4] = tp;
      if (tid<192) ((float*)gsum)[tid] = 0.f;
    }
    __syncthreads();  // b4
    // ---- P4: y = tanh(m1.Ut + m1b); ysum += (overlaps next P1)
    {
      sh8 tb[4];
      #pragma unroll
      for (int f=0;f<4;f++) tb[f] = *(const sh8*)&ut_sh[r16][f*32+g4*8];
      f32x4 ay={0.f,0.f,0.f,0.f};
      #pragma unroll
      for (int f=0;f<4;f++) ay = __builtin_amdgcn_mfma_f32_16x16x32_bf16(m1F[f], tb[f], ay,0,0,0);
      float4 m1bv = *(const float4*)&m1bL[q*16+g4*4];
      #pragma unroll
      for (int r=0;r<4;r++) ysum[r] += tanhf_(ay[r] + m1bv[r]);
    }
    cur ^= 1;
  }
  if (w<4){
    #pragma unroll
    for (int r=0;r<4;r++)
      ybf[(size_t)(b0+r16)*OUTD + q*16 + g4*4 + r] = __float2bfloat16(ysum[r]*(1.0f/TT));
  }
}

// ---------------- final: s = y @ Sy^T, log_softmax (|s|<=64, no max shift) --------
__global__ __launch_bounds__(256) void k_logits(
    const __hip_bfloat16* __restrict__ ybf, const __hip_bfloat16* __restrict__ Sy,
    float* __restrict__ denom, float* __restrict__ out, int pass) {
  __shared__ float dsum[64];
  int lane = threadIdx.x & 63;
  int w = threadIdx.x >> 6;
  int r16 = lane & 15, g4 = lane >> 4;
  int kof = g4 * 8;
  int tbase = blockIdx.x * 16 + w * 4;
  if (pass==0){
    if (threadIdx.x<64) dsum[threadIdx.x]=0.f;
    __syncthreads();
  }
  sh8 b0[4], b1[4];
  #pragma unroll
  for (int i=0;i<4;i++){
    if (tbase + i < NTILE) {
      const __hip_bfloat16* bp = Sy + ((size_t)((tbase+i)*16 + r16))*OUTD + kof;
      b0[i] = *(const sh8*)bp;
      b1[i] = *(const sh8*)(bp + 32);
    } else {
      sh8 z = {0,0,0,0,0,0,0,0};
      b0[i]=z; b1[i]=z;
    }
  }
  int bg0 = blockIdx.y * 4;
  for (int bgi=0; bgi<4; bgi++){
    int bg = bg0 + bgi;
    const __hip_bfloat16* ap = ybf + (bg*16 + r16)*OUTD + kof;
    sh8 a0 = *(const sh8*)ap;
    sh8 a1 = *(const sh8*)(ap+32);
    if (pass == 0){
      float part[4] = {0.f,0.f,0.f,0.f};
      #pragma unroll
      for (int i=0;i<4;i++){
        if (tbase + i < NTILE){
          f32x4 acc = {0.f,0.f,0.f,0.f};
          acc = __builtin_amdgcn_mfma_f32_16x16x32_bf16(a0,b0[i],acc,0,0,0);
          acc = __builtin_amdgcn_mfma_f32_16x16x32_bf16(a1,b1[i],acc,0,0,0);
          #pragma unroll
          for (int r=0;r<4;r++) part[r] += __expf(acc[r]);
        }
      }
      #pragma unroll
      for (int r=0;r<4;r++){
        float p = part[r];
        p += __shfl_xor(p,1,16); p += __shfl_xor(p,2,16);
        p += __shfl_xor(p,4,16); p += __shfl_xor(p,8,16);
        if (r16==0) atomicAdd(&dsum[bgi*16 + g4*4 + r], p);
      }
    } else {
      float lse[4];
      #pragma unroll
      for (int r=0;r<4;r++) lse[r] = logf(denom[(size_t)(bg*16 + g4*4 + r)*DSTR]);
      #pragma unroll
      for (int i=0;i<4;i++){
        if (tbase + i < NTILE){
          f32x4 acc = {0.f,0.f,0.f,0.f};
          acc = __builtin_amdgcn_mfma_f32_16x16x32_bf16(a0,b0[i],acc,0,0,0);
          acc = __builtin_amdgcn_mfma_f32_16x16x32_bf16(a1,b1[i],acc,0,0,0);
          int vc = (tbase+i)*16 + r16;
          #pragma unroll
          for (int r=0;r<4;r++)
            out[(size_t)(bg*16 + g4*4 + r)*VV + vc] = acc[r] - lse[r];
        }
      }
    }
  }
  if (pass==0){
    __syncthreads();
    if (threadIdx.x<64)
      atomicAdd(&denom[(size_t)(bg0*16 + threadIdx.x)*DSTR], dsum[threadIdx.x]);
  }
}

extern "C" void kernel_launch(void* const* d_in, const int* in_sizes, int n_in,
                              void* d_out, int out_size, void* d_ws, size_t ws_size,
                              hipStream_t stream) {
  const int*   X    = (const int*)  d_in[0];
  const float* E    = (const float*)d_in[1];
  const float* KBE  = (const float*)d_in[2];
  const float* rmat = (const float*)d_in[3];
  const float* Wih  = (const float*)d_in[4];
  const float* Whh  = (const float*)d_in[5];
  const float* bih  = (const float*)d_in[6];
  const float* bhh  = (const float*)d_in[7];
  const float* uW   = (const float*)d_in[8];
  const float* ub   = (const float*)d_in[9];
  const float* eaW  = (const float*)d_in[10];
  const float* eab  = (const float*)d_in[11];
  const float* u2W  = (const float*)d_in[12];
  const float* u2b  = (const float*)d_in[13];
  const float* m1W  = (const float*)d_in[14];
  const float* m1b  = (const float*)d_in[15];
  const float* m2W  = (const float*)d_in[16];
  const float* m2b  = (const float*)d_in[17];
  float* outp = (float*)d_out;

  char* p = (char*)d_ws;
  float* WihT   = (float*)p;            p += (size_t)EMB*G3H*4;
  float* eaWT   = (float*)p;            p += (size_t)KBD*KBD*4;
  float* gi_pre = (float*)p;            p += (size_t)BB*TT*G3H*4;
  float* ea_pre = (float*)p;            p += (size_t)BB*TT*KBD*4;
  float* denom  = (float*)p;            p += (size_t)BB*DSTR*4;
  __hip_bfloat16* ybf    = (__hip_bfloat16*)p; p += (size_t)BB*OUTD*2;
  __hip_bfloat16* Sy     = (__hip_bfloat16*)p; p += (size_t)VV*OUTD*2;

  k_trans<<<32,256,0,stream>>>(Wih,eaW,WihT,eaWT);
  k_pre<<<(BB*TT)/PREP,384,0,stream>>>(X,E,KBE,WihT,bih,bhh,eaWT,eab,gi_pre,ea_pre);
  hipMemsetAsync(denom, 0, BB*DSTR*sizeof(float), stream);
  k_scan<<<641,512,0,stream>>>(gi_pre,ea_pre,Whh,bhh,uW,ub,rmat,u2W,u2b,m1W,m1b,ybf,
                               E,KBE,m2W,m2b,Sy);
  dim3 g1((NTILE + 15)/16, 4, 1);
  k_logits<<<g1,256,0,stream>>>(ybf,Sy,denom,outp,0);
  k_logits<<<g1,256,0,stream>>>(ybf,Sy,denom,outp,1);
}

// Round 5
// 276.751 us; speedup vs baseline: 5.6665x; 1.2020x over previous
//
#include <hip/hip_runtime.h>
#include <hip/hip_bf16.h>
#include <math.h>

#define BB 256
#define TT 50
#define VV 100000
#define EMB 64
#define KBD 64
#define HH 128
#define NF 10
#define OUTD 64
#define G3H 384
#define NTILE 6250   // VV/16
#define DSTR 16      // denom stride (floats)

typedef __attribute__((ext_vector_type(8))) short sh8;
typedef __attribute__((ext_vector_type(4))) short sh4;
typedef __attribute__((ext_vector_type(2))) short sh2;
typedef __attribute__((ext_vector_type(4))) float f32x4;

__device__ __forceinline__ float frcp(float x){ return __builtin_amdgcn_rcpf(x); }
__device__ __forceinline__ float sigm(float x){ return frcp(1.0f+__expf(-x)); }
__device__ __forceinline__ float tanhf_(float x){ return 1.0f - 2.0f*frcp(__expf(2.0f*x)+1.0f); }
__device__ __forceinline__ short f2bs(float f){ __hip_bfloat16 h=__float2bfloat16(f); return *reinterpret_cast<short*>(&h); }
__device__ __forceinline__ sh8 ldfrag(const float* p){
  float4 a = *(const float4*)p; float4 b = *(const float4*)(p+4);
  sh8 v;
  v[0]=f2bs(a.x); v[1]=f2bs(a.y); v[2]=f2bs(a.z); v[3]=f2bs(a.w);
  v[4]=f2bs(b.x); v[5]=f2bs(b.y); v[6]=f2bs(b.z); v[7]=f2bs(b.w);
  return v;
}

// ---------------- transpose weights for k_pre ----------------
__global__ void k_trans(const float* __restrict__ Wih, const float* __restrict__ eaW,
                        float* __restrict__ WihT, float* __restrict__ eaWT) {
  int stride = gridDim.x*blockDim.x;
  int tid0 = blockIdx.x*blockDim.x + threadIdx.x;
  for (int i=tid0; i<G3H*EMB; i+=stride){ int j=i/EMB, k=i%EMB; WihT[k*G3H+j]=Wih[i]; }
  for (int i=tid0; i<KBD*KBD; i+=stride){ int j=i/KBD, k=i%KBD; eaWT[k*KBD+j]=eaW[i]; }
}

// ---------------- precompute gi[b,t,384] (bih + bhh(r,z) folded) and ea ----------
#define PREP 32
__global__ __launch_bounds__(384) void k_pre(
    const int* __restrict__ X, const float* __restrict__ E, const float* __restrict__ KBE,
    const float* __restrict__ WihT, const float* __restrict__ bih, const float* __restrict__ bhh,
    const float* __restrict__ eaWT, const float* __restrict__ eab,
    float* __restrict__ gi_pre, float* __restrict__ ea_pre) {
  __shared__ float xeL[PREP][EMB];
  __shared__ float kbL[PREP][KBD];
  int tid = threadIdx.x;
  int base = blockIdx.x * PREP;
  for (int i=tid; i<PREP*EMB; i+=384){
    int p=i>>6, k=i&63; int x = X[base+p];
    xeL[p][k] = x ? E[(size_t)x*EMB+k] : 0.0f;
    kbL[p][k] = x ? KBE[(size_t)x*KBD+k] : 0.0f;
  }
  __syncthreads();
  {
    int j = tid;
    float acc[PREP];
    #pragma unroll
    for (int p=0;p<PREP;p++) acc[p]=0.f;
    for (int k=0;k<EMB;k++){
      float w = WihT[k*G3H+j];
      #pragma unroll
      for (int p=0;p<PREP;p++) acc[p] += w*xeL[p][k];
    }
    float bj = bih[j] + (j < 2*HH ? bhh[j] : 0.0f);
    for (int p=0;p<PREP;p++) gi_pre[((size_t)(base+p))*G3H + j] = acc[p]+bj;
  }
  {
    int d = tid & 63; int pg = tid >> 6;
    float bd = eab[d];
    for (int p=pg; p<PREP; p+=6){
      float acc=0.f;
      #pragma unroll 8
      for (int k=0;k<KBD;k++) acc += eaWT[k*KBD+d]*kbL[p][k];
      ea_pre[((size_t)(base+p))*KBD + d] = tanhf(acc + bd);
    }
  }
}

// ========== fused: blocks 0..15 = scan (16 rows each); blocks 16..640 = Sy ==========
__global__ __launch_bounds__(512,2) void k_scan(
    const float* __restrict__ gi_pre, const float* __restrict__ ea_pre,
    const float* __restrict__ Whh, const float* __restrict__ bhh,
    const float* __restrict__ uW, const float* __restrict__ ub,
    const float* __restrict__ rmat,
    const float* __restrict__ u2W, const float* __restrict__ u2b,
    const float* __restrict__ m1W, const float* __restrict__ m1b,
    __hip_bfloat16* __restrict__ ybf,
    const float* __restrict__ E, const float* __restrict__ KBE,
    const float* __restrict__ m2W, const float* __restrict__ m2b,
    __hip_bfloat16* __restrict__ Sy) {
  // pipelined LDS state (strides chosen for 4-bank row skew: 200/72/136 bf16)
  __shared__ __hip_bfloat16 hcat[4][16][200];   // h[0:128], AC[128:192]
  __shared__ __hip_bfloat16 u_sh[2][16][72];
  __shared__ __hip_bfloat16 ut_sh[2][16][136];

  const int tid = threadIdx.x;
  const int w = tid>>6, l = tid&63, r16 = l&15, g4 = l>>4;

  if (blockIdx.x >= 16) {
    // ---------------- Sy path ----------------
    int kof = g4*8;
    sh8 bbf[4][4];
    float bias[4];
    #pragma unroll
    for (int nt=0;nt<4;nt++){
      int o = nt*16 + r16;
      bias[nt] = m2b[o];
      #pragma unroll
      for (int ks=0;ks<4;ks++) bbf[nt][ks] = ldfrag(m2W + o*128 + ks*32 + kof);
    }
    int wid = (blockIdx.x-16)*8 + w;
    for (int tile=wid; tile<NTILE; tile+=5000){
      int v = tile*16 + r16;
      sh8 aa[4];
      const float* ep = E + (size_t)v*EMB + kof;
      const float* kp = KBE + (size_t)v*KBD + kof;
      aa[0] = ldfrag(ep); aa[1] = ldfrag(ep+32);
      aa[2] = ldfrag(kp); aa[3] = ldfrag(kp+32);
      if (v==0){ sh8 z={0,0,0,0,0,0,0,0}; aa[0]=z;aa[1]=z;aa[2]=z;aa[3]=z; }
      f32x4 acc[4];
      #pragma unroll
      for (int nt=0;nt<4;nt++){ f32x4 z={0.f,0.f,0.f,0.f}; acc[nt]=z; }
      #pragma unroll
      for (int nt=0;nt<4;nt++)
        #pragma unroll
        for (int ks=0;ks<4;ks++)
          acc[nt] = __builtin_amdgcn_mfma_f32_16x16x32_bf16(aa[ks],bbf[nt][ks],acc[nt],0,0,0);
      #pragma unroll
      for (int nt=0;nt<4;nt++){
        #pragma unroll
        for (int r=0;r<4;r++){
          int vv = tile*16 + g4*4 + r;
          Sy[(size_t)vv*OUTD + nt*16 + r16] = __float2bfloat16(tanhf_(acc[nt][r] + bias[nt]));
        }
      }
    }
    return;
  }

  // ---------------- scan path ----------------
  const int b0 = blockIdx.x*16;
  const int rowp = l>>5;            // 0/1
  const int myrow = 2*w + rowp;     // MN ownership: wave w owns rows 2w,2w+1
  const int d0 = (l&31)*2;          // 2 d-values per lane

  for (int i=tid;i<4*16*200;i+=512) ((short*)hcat)[i]=0;

  // persistent weight fragments
  sh8 whhF[3][4];
  #pragma unroll
  for (int i=0;i<3;i++)
    #pragma unroll
    for (int f=0;f<4;f++)
      whhF[i][f] = ldfrag(Whh + (size_t)((i*8+w)*16 + r16)*HH + f*32 + g4*8);
  sh8 u2F[6];
  #pragma unroll
  for (int f=0;f<6;f++) u2F[f] = ldfrag(u2W + (size_t)(w*16+r16)*(HH+KBD) + f*32 + g4*8);
  sh8 wF4[4];   // uW (waves 0-3) / m1W (waves 4-7)
  {
    const float* wsrc = (w<4) ? (uW + (size_t)(w*16+r16)*HH) : (m1W + (size_t)((w-4)*16+r16)*HH);
    #pragma unroll
    for (int f=0;f<4;f++) wF4[f] = ldfrag(wsrc + f*32 + g4*8);
  }
  sh8 rmF[2];
  #pragma unroll
  for (int f=0;f<2;f++){
    sh8 z = {0,0,0,0,0,0,0,0};
    if (r16 < NF) z = ldfrag(rmat + (size_t)r16*KBD + f*32 + g4*8);
    rmF[f] = z;
  }
  float rmA[NF], rmB[NF], mnA[NF], mnB[NF];
  #pragma unroll
  for (int n=0;n<NF;n++){
    rmA[n] = rmat[n*KBD + d0]; rmB[n] = rmat[n*KBD + d0 + 1];
    mnA[n] = 0.f; mnB[n] = 0.f;
  }
  float4 bhn = *(const float4*)(bhh + 2*HH + w*16 + g4*4);
  float4 b4v = (w<4) ? *(const float4*)(ub + w*16+g4*4) : *(const float4*)(m1b + (w-4)*16+g4*4);
  float4 u2bv = *(const float4*)(u2b + w*16+g4*4);

  float h_old[4] = {0.f,0.f,0.f,0.f};
  float ysum[4] = {0.f,0.f,0.f,0.f};

  const float* gi_row = gi_pre + (size_t)(b0+r16)*TT*G3H;
  const float* ea_row = ea_pre + (size_t)(b0+myrow)*TT*KBD;
  float4 gi0 = *(const float4*)(gi_row + 0*128 + w*16 + g4*4);
  float4 gi1 = *(const float4*)(gi_row + 1*128 + w*16 + g4*4);
  float4 gi2 = *(const float4*)(gi_row + 2*128 + w*16 + g4*4);
  float2 eaCur = {0.f, 0.f};

  __syncthreads();

  for (int s=0; s<TT+4; ++s){
    const int s0 = s&3, sm1 = (s+3)&3, sm2 = (s+2)&3, sm3 = (s+1)&3;
    const int pW = (s+1)&1;   // u_sh/ut_sh write slots
    const int pR = s&1;       // read slots

    // prefetch next-step gi/ea (consumed next segment; L2-resident)
    int sg = (s+1<TT)? s+1 : TT-1;
    int se = (s<TT)? s : TT-1;
    float4 giN0 = *(const float4*)(gi_row + sg*G3H + 0*128 + w*16 + g4*4);
    float4 giN1 = *(const float4*)(gi_row + sg*G3H + 1*128 + w*16 + g4*4);
    float4 giN2 = *(const float4*)(gi_row + sg*G3H + 2*128 + w*16 + g4*4);
    float2 eaN  = *(const float2*)(ea_row + se*KBD + d0);

    // ---- read h(s-1) fragments (for gh and U)
    sh8 hb[4];
    if (s<=TT){
      #pragma unroll
      for (int f=0;f<4;f++) hb[f] = *(const sh8*)&hcat[sm1][r16][f*32+g4*8];
    }
    // ---- R: h(s) = GRU(h(s-1), gi(s))   [s<TT]
    if (s<TT){
      f32x4 a0={0.f,0.f,0.f,0.f}, a1=a0, a2=a0;
      #pragma unroll
      for (int f=0;f<4;f++){
        a0 = __builtin_amdgcn_mfma_f32_16x16x32_bf16(whhF[0][f], hb[f], a0,0,0,0);
        a1 = __builtin_amdgcn_mfma_f32_16x16x32_bf16(whhF[1][f], hb[f], a1,0,0,0);
        a2 = __builtin_amdgcn_mfma_f32_16x16x32_bf16(whhF[2][f], hb[f], a2,0,0,0);
      }
      sh4 hp;
      #pragma unroll
      for (int r=0;r<4;r++){
        float rr = sigm(gi0[r] + a0[r]);
        float zz = sigm(gi1[r] + a1[r]);
        float nn = tanhf_(gi2[r] + rr*(a2[r] + bhn[r]));
        h_old[r] = (1.f-zz)*nn + zz*h_old[r];
        hp[r] = f2bs(h_old[r]);
      }
      *(sh4*)&hcat[s0][r16][w*16+g4*4] = hp;
    }
    // ---- U(s-1) = tanh(uW.h(s-1)+ub)   [waves 0-3, 1<=s<=TT]
    if (w<4 && s>=1 && s<=TT){
      f32x4 au={0.f,0.f,0.f,0.f};
      #pragma unroll
      for (int f=0;f<4;f++) au = __builtin_amdgcn_mfma_f32_16x16x32_bf16(wF4[f], hb[f], au,0,0,0);
      sh4 up;
      #pragma unroll
      for (int r=0;r<4;r++) up[r] = f2bs(tanhf_(au[r] + b4v[r]));
      *(sh4*)&u_sh[pW][r16][w*16+g4*4] = up;
    }
    // ---- attn(s-2): logits -> softmax -> aw -> AC (uses MN(s-2) = mn pre-update)
    if (s>=2 && s<=TT+1){
      sh8 uf[2];
      #pragma unroll
      for (int f=0;f<2;f++) uf[f] = *(const sh8*)&u_sh[pR][r16][f*32+g4*8];
      f32x4 al={0.f,0.f,0.f,0.f};
      #pragma unroll
      for (int f=0;f<2;f++) al = __builtin_amdgcn_mfma_f32_16x16x32_bf16(rmF[f], uf[f], al,0,0,0);
      float mx = -1e30f;
      #pragma unroll
      for (int r=0;r<4;r++){ if (g4*4+r < NF) mx = fmaxf(mx, al[r]); }
      mx = fmaxf(mx, __shfl_xor(mx,16));
      mx = fmaxf(mx, __shfl_xor(mx,32));
      float av[4]; float ssum=0.f;
      #pragma unroll
      for (int r=0;r<4;r++){ av[r] = (g4*4+r < NF) ? __expf(al[r]-mx) : 0.f; ssum += av[r]; }
      ssum += __shfl_xor(ssum,16); ssum += __shfl_xor(ssum,32);
      float inv = frcp(ssum);
      #pragma unroll
      for (int r=0;r<4;r++) av[r] *= inv;
      // gather aw for my MN rows via shfl (src lane holds row=myrow, n-group)
      float ac0=0.f, ac1=0.f;
      #pragma unroll
      for (int n=0;n<NF;n++){
        float awn = __shfl(av[n&3], (n>>2)*16 + myrow);
        ac0 += mnA[n]*awn;
        ac1 += mnB[n]*awn;
      }
      sh2 acp; acp[0]=f2bs(ac0); acp[1]=f2bs(ac1);
      *(sh2*)&hcat[sm2][myrow][HH + d0] = acp;
    }
    // ---- MN update for step s-1 (gate uses MN(s-2), ea(s-1))   [1<=s<=TT]
    if (s>=1 && s<=TT){
      #pragma unroll
      for (int n=0;n<NF;n++){
        float e0 = eaCur.x + rmA[n], e1 = eaCur.y + rmB[n];
        float p = mnA[n]*e0 + mnB[n]*e1;
        p += __shfl_xor(p,1); p += __shfl_xor(p,2); p += __shfl_xor(p,4);
        p += __shfl_xor(p,8); p += __shfl_xor(p,16);
        float g = sigm(p);
        mnA[n] += g*(e0 - mnA[n]);
        mnB[n] += g*(e1 - mnB[n]);
      }
    }
    // ---- Ut(s-3) = tanh(u2.[h;AC](s-3)+u2b)   [3<=s<=TT+2]
    if (s>=3 && s<=TT+2){
      sh8 cb[6];
      #pragma unroll
      for (int f=0;f<6;f++) cb[f] = *(const sh8*)&hcat[sm3][r16][f*32+g4*8];
      f32x4 at={0.f,0.f,0.f,0.f};
      #pragma unroll
      for (int f=0;f<6;f++) at = __builtin_amdgcn_mfma_f32_16x16x32_bf16(u2F[f], cb[f], at,0,0,0);
      sh4 tp;
      #pragma unroll
      for (int r=0;r<4;r++) tp[r] = f2bs(tanhf_(at[r] + u2bv[r]));
      *(sh4*)&ut_sh[pW][r16][w*16+g4*4] = tp;
    }
    // ---- y(s-4) = tanh(m1.Ut(s-4)+m1b); ysum +=   [waves 4-7, 4<=s<=TT+3]
    if (w>=4 && s>=4 && s<=TT+3){
      sh8 tb[4];
      #pragma unroll
      for (int f=0;f<4;f++) tb[f] = *(const sh8*)&ut_sh[pR][r16][f*32+g4*8];
      f32x4 ay={0.f,0.f,0.f,0.f};
      #pragma unroll
      for (int f=0;f<4;f++) ay = __builtin_amdgcn_mfma_f32_16x16x32_bf16(wF4[f], tb[f], ay,0,0,0);
      #pragma unroll
      for (int r=0;r<4;r++) ysum[r] += tanhf_(ay[r] + b4v[r]);
    }
    gi0=giN0; gi1=giN1; gi2=giN2; eaCur=eaN;
    __syncthreads();
  }
  if (w>=4){
    #pragma unroll
    for (int r=0;r<4;r++)
      ybf[(size_t)(b0+r16)*OUTD + (w-4)*16 + g4*4 + r] = __float2bfloat16(ysum[r]*(1.0f/TT));
  }
}

// ---------------- final: s = y @ Sy^T, log_softmax (|s|<=64, no max shift) --------
__global__ __launch_bounds__(256) void k_logits(
    const __hip_bfloat16* __restrict__ ybf, const __hip_bfloat16* __restrict__ Sy,
    float* __restrict__ denom, float* __restrict__ out, int pass) {
  __shared__ float dsum[64];
  int lane = threadIdx.x & 63;
  int w = threadIdx.x >> 6;
  int r16 = lane & 15, g4 = lane >> 4;
  int kof = g4 * 8;
  int tbase = blockIdx.x * 16 + w * 4;
  if (pass==0){
    if (threadIdx.x<64) dsum[threadIdx.x]=0.f;
    __syncthreads();
  }
  sh8 b0[4], b1[4];
  #pragma unroll
  for (int i=0;i<4;i++){
    if (tbase + i < NTILE) {
      const __hip_bfloat16* bp = Sy + ((size_t)((tbase+i)*16 + r16))*OUTD + kof;
      b0[i] = *(const sh8*)bp;
      b1[i] = *(const sh8*)(bp + 32);
    } else {
      sh8 z = {0,0,0,0,0,0,0,0};
      b0[i]=z; b1[i]=z;
    }
  }
  int bg0 = blockIdx.y * 4;
  for (int bgi=0; bgi<4; bgi++){
    int bg = bg0 + bgi;
    const __hip_bfloat16* ap = ybf + (bg*16 + r16)*OUTD + kof;
    sh8 a0 = *(const sh8*)ap;
    sh8 a1 = *(const sh8*)(ap+32);
    if (pass == 0){
      float part[4] = {0.f,0.f,0.f,0.f};
      #pragma unroll
      for (int i=0;i<4;i++){
        if (tbase + i < NTILE){
          f32x4 acc = {0.f,0.f,0.f,0.f};
          acc = __builtin_amdgcn_mfma_f32_16x16x32_bf16(a0,b0[i],acc,0,0,0);
          acc = __builtin_amdgcn_mfma_f32_16x16x32_bf16(a1,b1[i],acc,0,0,0);
          #pragma unroll
          for (int r=0;r<4;r++) part[r] += __expf(acc[r]);
        }
      }
      #pragma unroll
      for (int r=0;r<4;r++){
        float p = part[r];
        p += __shfl_xor(p,1,16); p += __shfl_xor(p,2,16);
        p += __shfl_xor(p,4,16); p += __shfl_xor(p,8,16);
        if (r16==0) atomicAdd(&dsum[bgi*16 + g4*4 + r], p);
      }
    } else {
      float lse[4];
      #pragma unroll
      for (int r=0;r<4;r++) lse[r] = logf(denom[(size_t)(bg*16 + g4*4 + r)*DSTR]);
      #pragma unroll
      for (int i=0;i<4;i++){
        if (tbase + i < NTILE){
          f32x4 acc = {0.f,0.f,0.f,0.f};
          acc = __builtin_amdgcn_mfma_f32_16x16x32_bf16(a0,b0[i],acc,0,0,0);
          acc = __builtin_amdgcn_mfma_f32_16x16x32_bf16(a1,b1[i],acc,0,0,0);
          int vc = (tbase+i)*16 + r16;
          #pragma unroll
          for (int r=0;r<4;r++)
            out[(size_t)(bg*16 + g4*4 + r)*VV + vc] = acc[r] - lse[r];
        }
      }
    }
  }
  if (pass==0){
    __syncthreads();
    if (threadIdx.x<64)
      atomicAdd(&denom[(size_t)(bg0*16 + threadIdx.x)*DSTR], dsum[threadIdx.x]);
  }
}

extern "C" void kernel_launch(void* const* d_in, const int* in_sizes, int n_in,
                              void* d_out, int out_size, void* d_ws, size_t ws_size,
                              hipStream_t stream) {
  const int*   X    = (const int*)  d_in[0];
  const float* E    = (const float*)d_in[1];
  const float* KBE  = (const float*)d_in[2];
  const float* rmat = (const float*)d_in[3];
  const float* Wih  = (const float*)d_in[4];
  const float* Whh  = (const float*)d_in[5];
  const float* bih  = (const float*)d_in[6];
  const float* bhh  = (const float*)d_in[7];
  const float* uW   = (const float*)d_in[8];
  const float* ub   = (const float*)d_in[9];
  const float* eaW  = (const float*)d_in[10];
  const float* eab  = (const float*)d_in[11];
  const float* u2W  = (const float*)d_in[12];
  const float* u2b  = (const float*)d_in[13];
  const float* m1W  = (const float*)d_in[14];
  const float* m1b  = (const float*)d_in[15];
  const float* m2W  = (const float*)d_in[16];
  const float* m2b  = (const float*)d_in[17];
  float* outp = (float*)d_out;

  char* p = (char*)d_ws;
  float* WihT   = (float*)p;            p += (size_t)EMB*G3H*4;
  float* eaWT   = (float*)p;            p += (size_t)KBD*KBD*4;
  float* gi_pre = (float*)p;            p += (size_t)BB*TT*G3H*4;
  float* ea_pre = (float*)p;            p += (size_t)BB*TT*KBD*4;
  float* denom  = (float*)p;            p += (size_t)BB*DSTR*4;
  __hip_bfloat16* ybf    = (__hip_bfloat16*)p; p += (size_t)BB*OUTD*2;
  __hip_bfloat16* Sy     = (__hip_bfloat16*)p; p += (size_t)VV*OUTD*2;

  k_trans<<<32,256,0,stream>>>(Wih,eaW,WihT,eaWT);
  k_pre<<<(BB*TT)/PREP,384,0,stream>>>(X,E,KBE,WihT,bih,bhh,eaWT,eab,gi_pre,ea_pre);
  hipMemsetAsync(denom, 0, BB*DSTR*sizeof(float), stream);
  k_scan<<<641,512,0,stream>>>(gi_pre,ea_pre,Whh,bhh,uW,ub,rmat,u2W,u2b,m1W,m1b,ybf,
                               E,KBE,m2W,m2b,Sy);
  dim3 g1((NTILE + 15)/16, 4, 1);
  k_logits<<<g1,256,0,stream>>>(ybf,Sy,denom,outp,0);
  k_logits<<<g1,256,0,stream>>>(ybf,Sy,denom,outp,1);
}